// Round 2
// baseline (936.968 us; speedup 1.0000x reference)
//
#include <hip/hip_runtime.h>
#include <math.h>

#define Bc 4
#define Nc 512
#define Pc 1024
#define Kc 20
#define SH_DIM 9
#define MUL 64
#define NBc 20
#define HID 100
#define Tc 3
#define CUTc 4.0f
#define Ec (Nc * Kc)        /* 10240 */
#define PEc (Pc * Kc)       /* 20480 */
#define NA (Bc * Nc)        /* 2048 */
#define NP (Bc * Pc)        /* 4096 */
#define ET (Bc * Ec)        /* 40960 */
#define PET (Bc * PEc)      /* 81920 */
#define FEAT (SH_DIM * MUL) /* 576 */

__device__ __forceinline__ float silu_f(float x) { return x / (1.0f + expf(-x)); }
__device__ __forceinline__ float sigmoid_f(float x) { return 1.0f / (1.0f + expf(-x)); }

// ---------------------------------------------------------------------------
// Pass 1: count edges per destination
// ---------------------------------------------------------------------------
__global__ void count_kernel(const int* __restrict__ edges, int* __restrict__ cnt,
                             int Eper, int Etot, int dst_stride)
{
    int e = blockIdx.x * blockDim.x + threadIdx.x;
    if (e >= Etot) return;
    int b = e / Eper;
    atomicAdd(&cnt[edges[e * 2 + 1] + b * dst_stride], 1);
}

// ---------------------------------------------------------------------------
// Single-block exclusive scan: off[0..n] plus cursor copy
// ---------------------------------------------------------------------------
__global__ void scan_kernel(const int* __restrict__ cnt, int* __restrict__ off,
                            int* __restrict__ cur, int n)
{
    __shared__ int part[256];
    int t = threadIdx.x;
    int per = (n + 255) / 256;
    int lo = t * per, hi = min(lo + per, n);
    int s = 0;
    for (int i = lo; i < hi; ++i) s += cnt[i];
    part[t] = s;
    __syncthreads();
    if (t == 0) {
        int run = 0;
        for (int i = 0; i < 256; ++i) { int v = part[i]; part[i] = run; run += v; }
        off[n] = run;
    }
    __syncthreads();
    int run = part[t];
    for (int i = lo; i < hi; ++i) { off[i] = run; cur[i] = run; run += cnt[i]; }
}

// ---------------------------------------------------------------------------
// Pass 2: geometry, written directly in CSR (dst-sorted) order
// ---------------------------------------------------------------------------
__global__ void geom_kernel(const float* __restrict__ pos_src,
                            const float* __restrict__ pos_dst,
                            const int*   __restrict__ edges,
                            const float* __restrict__ displ,
                            const float* __restrict__ cell,
                            int* __restrict__ cur,
                            float* __restrict__ sh_out,   // (Etot,9)  CSR order
                            float* __restrict__ rbf_out,  // (Etot,20) CSR order
                            int*   __restrict__ src_out,  // (Etot)    CSR order
                            int Eper, int Etot, int src_stride, int dst_stride)
{
    int e = blockIdx.x * blockDim.x + threadIdx.x;
    if (e >= Etot) return;
    int b = e / Eper;
    int sg = edges[e * 2 + 0] + b * src_stride;
    int dg = edges[e * 2 + 1] + b * dst_stride;
    const float* C = cell + b * 9;
    float d0 = displ[e * 3 + 0], d1 = displ[e * 3 + 1], d2 = displ[e * 3 + 2];
    float dx = d0 * C[0] + d1 * C[3] + d2 * C[6];
    float dy = d0 * C[1] + d1 * C[4] + d2 * C[7];
    float dz = d0 * C[2] + d1 * C[5] + d2 * C[8];
    float vx = pos_dst[dg * 3 + 0] - (pos_src[sg * 3 + 0] + dx);
    float vy = pos_dst[dg * 3 + 1] - (pos_src[sg * 3 + 1] + dy);
    float vz = pos_dst[dg * 3 + 2] - (pos_src[sg * 3 + 2] + dz);
    float r = sqrtf(vx * vx + vy * vy + vz * vz);
    float inv = 1.0f / fmaxf(r, 1e-9f);
    float x = vx * inv, y = vy * inv, z = vz * inv;
    const float s3 = 1.7320508075688772f;
    const float s5 = 2.23606797749979f;
    const float s15 = 3.872983346207417f;
    int pos = atomicAdd(&cur[dg], 1);
    float* sh = sh_out + (size_t)pos * 9;
    sh[0] = 1.0f;
    sh[1] = s3 * x;
    sh[2] = s3 * y;
    sh[3] = s3 * z;
    sh[4] = s15 * x * y;
    sh[5] = s15 * y * z;
    sh[6] = 0.5f * s5 * (3.0f * z * z - 1.0f);
    sh[7] = s15 * x * z;
    sh[8] = 0.5f * s15 * (x * x - y * y);
    const float step = CUTc / (NBc - 1);
    const float inv_sigma = (float)NBc / CUTc;
    float* rb = rbf_out + (size_t)pos * 20;
#pragma unroll
    for (int k = 0; k < NBc; ++k) {
        float t = (r - k * step) * inv_sigma;
        rb[k] = expf(-t * t);
    }
    src_out[pos] = sg;
}

// ---------------------------------------------------------------------------
// Embedding
// ---------------------------------------------------------------------------
__global__ void embed_kernel(const int* __restrict__ nodes, const float* __restrict__ Wemb,
                             float* __restrict__ h0)
{
    int idx = blockIdx.x * blockDim.x + threadIdx.x;
    if (idx >= NA * FEAT) return;
    int a = idx / FEAT;
    int r = idx % FEAT;
    int i = r / MUL;
    int c = r % MUL;
    h0[idx] = (i == 0) ? Wemb[nodes[a] * MUL + c] : 0.0f;
}

// ---------------------------------------------------------------------------
// Edge radial MLP: w[e][c] = (silu(rbf @ Wr1 + br1) @ Wr2 + br2)[c]
// One wave per edge; weights staged in LDS; hidden exchanged via shfl.
// ---------------------------------------------------------------------------
__global__ __launch_bounds__(256) void mlp_kernel(
    const float* __restrict__ rbf,   // (Etot,20) CSR order
    const float* __restrict__ Wr1, const float* __restrict__ br1,
    const float* __restrict__ Wr2, const float* __restrict__ br2,
    float* __restrict__ wout, int Etot)
{
    __shared__ float sW1[NBc * HID];  // 2000 floats
    __shared__ float sW2[HID * MUL];  // 6400 floats
    int t = threadIdx.x;
    for (int i = t; i < NBc * HID; i += 256) sW1[i] = Wr1[i];
    for (int i = t; i < HID * MUL; i += 256) sW2[i] = Wr2[i];
    __syncthreads();
    int c = t & 63;
    int c2 = (c < HID - MUL) ? (MUL + c) : c;  // safe 2nd-neuron index
    float b1a = br1[c];
    float b1b = (c < HID - MUL) ? br1[MUL + c] : 0.0f;
    float b2 = br2[c];
    int wglobal = __builtin_amdgcn_readfirstlane(blockIdx.x * 4 + (t >> 6));
    int nw = gridDim.x * 4;
    for (int e = wglobal; e < Etot; e += nw) {
        const float* rb = rbf + (size_t)e * NBc;  // wave-uniform -> scalar loads
        float h1 = b1a, h2 = b1b;
#pragma unroll
        for (int k = 0; k < NBc; ++k) {
            float rv = rb[k];
            h1 += rv * sW1[k * HID + c];
            h2 += rv * sW1[k * HID + c2];
        }
        float hs1 = silu_f(h1);
        float hs2 = silu_f(h2);
        float wv = b2;
#pragma unroll
        for (int j = 0; j < HID; ++j) {
            float hv = (j < MUL) ? __shfl(hs1, j, 64) : __shfl(hs2, j - MUL, 64);
            wv += hv * sW2[j * MUL + c];
        }
        wout[(size_t)e * MUL + c] = wv;
    }
}

// ---------------------------------------------------------------------------
// Gather/segment-sum: a[n][i][c] = (1/sqrt(K)) * sum_e sh[e][i] * s_src[e][c] * w[e][c]
// Wave per node, 4 waves/block, no barriers.
// ---------------------------------------------------------------------------
__global__ __launch_bounds__(256) void gather_kernel(
    const float* __restrict__ h_src, const int* __restrict__ off,
    const int* __restrict__ srcg, const float* __restrict__ sh,
    const float* __restrict__ wbuf, float* __restrict__ abuf, int n_out)
{
    int c = threadIdx.x & 63;
    int n = __builtin_amdgcn_readfirstlane(blockIdx.x * 4 + (threadIdx.x >> 6));
    if (n >= n_out) return;
    int e0 = off[n], e1 = off[n + 1];
    float acc[SH_DIM];
#pragma unroll
    for (int i = 0; i < SH_DIM; ++i) acc[i] = 0.0f;
    for (int p = e0; p < e1; ++p) {
        float wv = wbuf[(size_t)p * MUL + c];
        float s = h_src[(size_t)srcg[p] * FEAT + c];
        float sw = s * wv;
        const float* shp = sh + (size_t)p * SH_DIM;  // wave-uniform
#pragma unroll
        for (int i = 0; i < SH_DIM; ++i) acc[i] += shp[i] * sw;
    }
    const float isk = 0.22360679774997896f;  // 1/sqrt(20)
#pragma unroll
    for (int i = 0; i < SH_DIM; ++i)
        abuf[(size_t)n * FEAT + i * MUL + c] = acc[i] * isk;
}

// ---------------------------------------------------------------------------
// l=0 linear + silu + residual, and gate. Lane c holds W columns in VGPRs;
// a-rows are wave-uniform -> scalar loads -> pure VALU FMA.
// ---------------------------------------------------------------------------
__global__ __launch_bounds__(256) void gate_lin0_kernel(
    const float* __restrict__ abuf, const float* __restrict__ base,
    float* __restrict__ outb, float* __restrict__ gbuf,
    const float* __restrict__ Wl, const float* __restrict__ Wg, int n_out)
{
    int c = threadIdx.x & 63;
    float wl0[MUL], wg[MUL];
#pragma unroll
    for (int k = 0; k < MUL; ++k) { wl0[k] = Wl[k * MUL + c]; wg[k] = Wg[k * MUL + c]; }
    int wglobal = __builtin_amdgcn_readfirstlane(blockIdx.x * 4 + (threadIdx.x >> 6));
    int nw = gridDim.x * 4;
    for (int n = wglobal; n < n_out; n += nw) {
        const float* ar = abuf + (size_t)n * FEAT;  // row i=0, wave-uniform
        float u = 0.0f, g = 0.0f;
#pragma unroll
        for (int k = 0; k < MUL; ++k) { float av = ar[k]; u += av * wl0[k]; g += av * wg[k]; }
        size_t idx = (size_t)n * FEAT + c;
        outb[idx] = base[idx] + silu_f(u);
        gbuf[(size_t)n * MUL + c] = sigmoid_f(g);
    }
}

// ---------------------------------------------------------------------------
// l=1,2 linears + gate multiply + residual. blockIdx.y selects l.
// ---------------------------------------------------------------------------
__global__ __launch_bounds__(256) void lin12_kernel(
    const float* __restrict__ abuf, const float* __restrict__ base,
    float* __restrict__ outb, const float* __restrict__ gbuf,
    const float* __restrict__ Wl, int n_out)
{
    int c = threadIdx.x & 63;
    int l = blockIdx.y + 1;
    int ibase = (l == 1) ? 1 : 4;
    int ni = (l == 1) ? 3 : 5;
    const float* W = Wl + (size_t)l * MUL * MUL;
    float wcol[MUL];
#pragma unroll
    for (int k = 0; k < MUL; ++k) wcol[k] = W[k * MUL + c];
    int rows = n_out * ni;
    int wglobal = __builtin_amdgcn_readfirstlane(blockIdx.x * 4 + (threadIdx.x >> 6));
    int nw = gridDim.x * 4;
    for (int r = wglobal; r < rows; r += nw) {
        int n = r / ni, ii = r - n * ni;
        const float* ar = abuf + (size_t)n * FEAT + (size_t)(ibase + ii) * MUL;  // uniform
        float u = 0.0f;
#pragma unroll
        for (int k = 0; k < MUL; ++k) u += ar[k] * wcol[k];
        float g = gbuf[(size_t)n * MUL + c];
        size_t idx = (size_t)n * FEAT + (size_t)(ibase + ii) * MUL + c;
        outb[idx] = base[idx] + u * g;
    }
}

// ---------------------------------------------------------------------------
// Readout: out[n] = dot(p[n,0,:], W_out[:,0])
// ---------------------------------------------------------------------------
__global__ __launch_bounds__(64) void out_kernel(const float* __restrict__ p,
                                                 const float* __restrict__ Wout,
                                                 float* __restrict__ out)
{
    int n = blockIdx.x;
    int c = threadIdx.x;
    float v = p[(size_t)n * FEAT + c] * Wout[c];
#pragma unroll
    for (int o = 32; o > 0; o >>= 1) v += __shfl_down(v, o, 64);
    if (c == 0) out[n] = v;
}

// ---------------------------------------------------------------------------
extern "C" void kernel_launch(void* const* d_in, const int* in_sizes, int n_in,
                              void* d_out, int out_size, void* d_ws, size_t ws_size,
                              hipStream_t stream)
{
    const float* atom_xyz  = (const float*)d_in[0];
    const float* a_disp    = (const float*)d_in[1];
    const float* cell      = (const float*)d_in[2];
    const float* probe_xyz = (const float*)d_in[3];
    const float* p_disp    = (const float*)d_in[4];
    const float* W_embed   = (const float*)d_in[5];
    const float* Wr1       = (const float*)d_in[6];
    const float* br1       = (const float*)d_in[7];
    const float* Wr2       = (const float*)d_in[8];
    const float* br2       = (const float*)d_in[9];
    const float* Wl        = (const float*)d_in[10];
    const float* Wg        = (const float*)d_in[11];
    const float* pWr1      = (const float*)d_in[12];
    const float* pbr1      = (const float*)d_in[13];
    const float* pWr2      = (const float*)d_in[14];
    const float* pbr2      = (const float*)d_in[15];
    const float* pWl       = (const float*)d_in[16];
    const float* pWg       = (const float*)d_in[17];
    const float* W_out     = (const float*)d_in[18];
    const int*   atom_edges  = (const int*)d_in[19];
    const int*   probe_edges = (const int*)d_in[20];
    const int*   nodes       = (const int*)d_in[21];
    float* out = (float*)d_out;

    char* w = (char*)d_ws;
    auto alloc = [&](size_t bytes) -> void* {
        void* r = (void*)w;
        w += (bytes + 255) & ~(size_t)255;
        return r;
    };
    float* sh_a   = (float*)alloc((size_t)ET * 9 * 4);
    float* rbf_a  = (float*)alloc((size_t)ET * 20 * 4);
    int*   src_a  = (int*)alloc((size_t)ET * 4);
    int*   cnt_a  = (int*)alloc((size_t)NA * 4);
    int*   off_a  = (int*)alloc((size_t)(NA + 1) * 4);
    int*   cur_a  = (int*)alloc((size_t)NA * 4);
    float* sh_p   = (float*)alloc((size_t)PET * 9 * 4);
    float* rbf_p  = (float*)alloc((size_t)PET * 20 * 4);
    int*   src_p  = (int*)alloc((size_t)PET * 4);
    int*   cnt_p  = (int*)alloc((size_t)NP * 4);
    int*   off_p  = (int*)alloc((size_t)(NP + 1) * 4);
    int*   cur_p  = (int*)alloc((size_t)NP * 4);
    float* h0     = (float*)alloc((size_t)NA * FEAT * 4);
    float* rep0   = (float*)alloc((size_t)NA * FEAT * 4);
    float* rep1   = (float*)alloc((size_t)NA * FEAT * 4);
    float* rep2   = (float*)alloc((size_t)NA * FEAT * 4);
    float* pbuf   = (float*)alloc((size_t)NP * FEAT * 4);
    float* abuf   = (float*)alloc((size_t)NP * FEAT * 4);
    float* gbuf   = (float*)alloc((size_t)NP * MUL * 4);
    float* wbuf   = (float*)alloc((size_t)PET * MUL * 4);

    hipMemsetAsync(cnt_a, 0, (size_t)NA * 4, stream);
    hipMemsetAsync(cnt_p, 0, (size_t)NP * 4, stream);
    hipMemsetAsync(pbuf, 0, (size_t)NP * FEAT * 4, stream);

    // CSR build + geometry in CSR order
    count_kernel<<<(ET + 255) / 256, 256, 0, stream>>>(atom_edges, cnt_a, Ec, ET, Nc);
    count_kernel<<<(PET + 255) / 256, 256, 0, stream>>>(probe_edges, cnt_p, PEc, PET, Pc);
    scan_kernel<<<1, 256, 0, stream>>>(cnt_a, off_a, cur_a, NA);
    scan_kernel<<<1, 256, 0, stream>>>(cnt_p, off_p, cur_p, NP);
    geom_kernel<<<(ET + 255) / 256, 256, 0, stream>>>(
        atom_xyz, atom_xyz, atom_edges, a_disp, cell, cur_a,
        sh_a, rbf_a, src_a, Ec, ET, Nc, Nc);
    geom_kernel<<<(PET + 255) / 256, 256, 0, stream>>>(
        atom_xyz, probe_xyz, probe_edges, p_disp, cell, cur_p,
        sh_p, rbf_p, src_p, PEc, PET, Nc, Pc);

    embed_kernel<<<(NA * FEAT + 255) / 256, 256, 0, stream>>>(nodes, W_embed, h0);

    const float* hprev = h0;
    float* reps[3] = {rep0, rep1, rep2};
    dim3 lingrid(256, 2);

    // atom layers
    for (int t = 0; t < Tc; ++t) {
        mlp_kernel<<<1024, 256, 0, stream>>>(
            rbf_a, Wr1 + (size_t)t * NBc * HID, br1 + (size_t)t * HID,
            Wr2 + (size_t)t * HID * MUL, br2 + (size_t)t * MUL, wbuf, ET);
        gather_kernel<<<NA / 4, 256, 0, stream>>>(hprev, off_a, src_a, sh_a, wbuf, abuf, NA);
        gate_lin0_kernel<<<256, 256, 0, stream>>>(
            abuf, hprev, reps[t], gbuf,
            Wl + (size_t)t * 3 * MUL * MUL, Wg + (size_t)t * MUL * MUL, NA);
        lin12_kernel<<<lingrid, 256, 0, stream>>>(
            abuf, hprev, reps[t], gbuf, Wl + (size_t)t * 3 * MUL * MUL, NA);
        hprev = reps[t];
    }

    // probe layers (accumulate into pbuf)
    for (int t = 0; t < Tc; ++t) {
        mlp_kernel<<<1024, 256, 0, stream>>>(
            rbf_p, pWr1 + (size_t)t * NBc * HID, pbr1 + (size_t)t * HID,
            pWr2 + (size_t)t * HID * MUL, pbr2 + (size_t)t * MUL, wbuf, PET);
        gather_kernel<<<NP / 4, 256, 0, stream>>>(reps[t], off_p, src_p, sh_p, wbuf, abuf, NP);
        gate_lin0_kernel<<<256, 256, 0, stream>>>(
            abuf, pbuf, pbuf, gbuf,
            pWl + (size_t)t * 3 * MUL * MUL, pWg + (size_t)t * MUL * MUL, NP);
        lin12_kernel<<<lingrid, 256, 0, stream>>>(
            abuf, pbuf, pbuf, gbuf, pWl + (size_t)t * 3 * MUL * MUL, NP);
    }

    out_kernel<<<NP, 64, 0, stream>>>(pbuf, W_out, out);
}

// Round 3
// 693.937 us; speedup vs baseline: 1.3502x; 1.3502x over previous
//
#include <hip/hip_runtime.h>
#include <math.h>

#define Bc 4
#define Nc 512
#define Pc 1024
#define Kc 20
#define SH_DIM 9
#define MUL 64
#define NBc 20
#define HID 100
#define Tc 3
#define CUTc 4.0f
#define Ec (Nc * Kc)        /* 10240 */
#define PEc (Pc * Kc)       /* 20480 */
#define NA (Bc * Nc)        /* 2048 */
#define NP (Bc * Pc)        /* 4096 */
#define ET (Bc * Ec)        /* 40960 */
#define PET (Bc * PEc)      /* 81920 */
#define FEAT (SH_DIM * MUL) /* 576 */

__device__ __forceinline__ float silu_f(float x) { return x / (1.0f + __expf(-x)); }
__device__ __forceinline__ float sigmoid_f(float x) { return 1.0f / (1.0f + __expf(-x)); }

// ---------------------------------------------------------------------------
// Pass 1: count edges per destination
// ---------------------------------------------------------------------------
__global__ void count_kernel(const int* __restrict__ edges, int* __restrict__ cnt,
                             int Eper, int Etot, int dst_stride)
{
    int e = blockIdx.x * blockDim.x + threadIdx.x;
    if (e >= Etot) return;
    int b = e / Eper;
    atomicAdd(&cnt[edges[e * 2 + 1] + b * dst_stride], 1);
}

// ---------------------------------------------------------------------------
// Single-block exclusive scan: off[0..n] plus cursor copy
// ---------------------------------------------------------------------------
__global__ void scan_kernel(const int* __restrict__ cnt, int* __restrict__ off,
                            int* __restrict__ cur, int n)
{
    __shared__ int part[256];
    int t = threadIdx.x;
    int per = (n + 255) / 256;
    int lo = t * per, hi = min(lo + per, n);
    int s = 0;
    for (int i = lo; i < hi; ++i) s += cnt[i];
    part[t] = s;
    __syncthreads();
    if (t == 0) {
        int run = 0;
        for (int i = 0; i < 256; ++i) { int v = part[i]; part[i] = run; run += v; }
        off[n] = run;
    }
    __syncthreads();
    int run = part[t];
    for (int i = lo; i < hi; ++i) { off[i] = run; cur[i] = run; run += cnt[i]; }
}

// ---------------------------------------------------------------------------
// Pass 2: geometry, written directly in CSR (dst-sorted) order
// ---------------------------------------------------------------------------
__global__ void geom_kernel(const float* __restrict__ pos_src,
                            const float* __restrict__ pos_dst,
                            const int*   __restrict__ edges,
                            const float* __restrict__ displ,
                            const float* __restrict__ cell,
                            int* __restrict__ cur,
                            float* __restrict__ sh_out,   // (Etot,9)  CSR order
                            float* __restrict__ rbf_out,  // (Etot,20) CSR order
                            int*   __restrict__ src_out,  // (Etot)    CSR order
                            int Eper, int Etot, int src_stride, int dst_stride)
{
    int e = blockIdx.x * blockDim.x + threadIdx.x;
    if (e >= Etot) return;
    int b = e / Eper;
    int sg = edges[e * 2 + 0] + b * src_stride;
    int dg = edges[e * 2 + 1] + b * dst_stride;
    const float* C = cell + b * 9;
    float d0 = displ[e * 3 + 0], d1 = displ[e * 3 + 1], d2 = displ[e * 3 + 2];
    float dx = d0 * C[0] + d1 * C[3] + d2 * C[6];
    float dy = d0 * C[1] + d1 * C[4] + d2 * C[7];
    float dz = d0 * C[2] + d1 * C[5] + d2 * C[8];
    float vx = pos_dst[dg * 3 + 0] - (pos_src[sg * 3 + 0] + dx);
    float vy = pos_dst[dg * 3 + 1] - (pos_src[sg * 3 + 1] + dy);
    float vz = pos_dst[dg * 3 + 2] - (pos_src[sg * 3 + 2] + dz);
    float r = sqrtf(vx * vx + vy * vy + vz * vz);
    float inv = 1.0f / fmaxf(r, 1e-9f);
    float x = vx * inv, y = vy * inv, z = vz * inv;
    const float s3 = 1.7320508075688772f;
    const float s5 = 2.23606797749979f;
    const float s15 = 3.872983346207417f;
    int pos = atomicAdd(&cur[dg], 1);
    float* sh = sh_out + (size_t)pos * 9;
    sh[0] = 1.0f;
    sh[1] = s3 * x;
    sh[2] = s3 * y;
    sh[3] = s3 * z;
    sh[4] = s15 * x * y;
    sh[5] = s15 * y * z;
    sh[6] = 0.5f * s5 * (3.0f * z * z - 1.0f);
    sh[7] = s15 * x * z;
    sh[8] = 0.5f * s15 * (x * x - y * y);
    const float step = CUTc / (NBc - 1);
    const float inv_sigma = (float)NBc / CUTc;
    float* rb = rbf_out + (size_t)pos * 20;
#pragma unroll
    for (int k = 0; k < NBc; ++k) {
        float t = (r - k * step) * inv_sigma;
        rb[k] = __expf(-t * t);
    }
    src_out[pos] = sg;
}

// ---------------------------------------------------------------------------
// W1 transpose: w1t_all[t6][j][k] = W1[t6][k][j]  (t6: 0-2 atom, 3-5 probe)
// ---------------------------------------------------------------------------
__global__ void transpose_w1_kernel(const float* __restrict__ Wr1,
                                    const float* __restrict__ pWr1,
                                    float* __restrict__ w1t_all)
{
    int idx = blockIdx.x * 256 + threadIdx.x;
    if (idx >= 6 * HID * NBc) return;
    int t6 = idx / (HID * NBc);
    int rem = idx % (HID * NBc);
    int j = rem / NBc;
    int k = rem % NBc;
    const float* src = (t6 < 3) ? (Wr1 + (size_t)t6 * NBc * HID)
                                : (pWr1 + (size_t)(t6 - 3) * NBc * HID);
    w1t_all[idx] = src[k * HID + j];
}

// ---------------------------------------------------------------------------
// Embedding
// ---------------------------------------------------------------------------
__global__ void embed_kernel(const int* __restrict__ nodes, const float* __restrict__ Wemb,
                             float* __restrict__ h0)
{
    int idx = blockIdx.x * blockDim.x + threadIdx.x;
    if (idx >= NA * FEAT) return;
    int a = idx / FEAT;
    int r = idx % FEAT;
    int i = r / MUL;
    int c = r % MUL;
    h0[idx] = (i == 0) ? Wemb[nodes[a] * MUL + c] : 0.0f;
}

// ---------------------------------------------------------------------------
// Edge radial MLP, one edge per LANE. All weights consumed as wave-uniform
// scalar (SGPR) operands; per-lane state: rbf[20], h[10], acc[64] in VGPRs.
// No LDS, no shuffles, no vector loads in the hot loop.
// ---------------------------------------------------------------------------
__global__ __launch_bounds__(64) void mlp_kernel(
    const float* __restrict__ rbf,    // (Etot,20) CSR order
    const float* __restrict__ w1t,    // (100,20) transposed layer slice
    const float* __restrict__ br1,    // (100)
    const float* __restrict__ Wr2,    // (100,64)
    const float* __restrict__ br2,    // (64)
    float* __restrict__ wout,         // (Etot,64)
    int Etot)
{
    int e = blockIdx.x * 64 + threadIdx.x;
    if (e >= Etot) return;

    float rb[NBc];
    const float4* rp = (const float4*)(rbf + (size_t)e * NBc);
#pragma unroll
    for (int q = 0; q < NBc / 4; ++q) {
        float4 v = rp[q];
        rb[q * 4 + 0] = v.x; rb[q * 4 + 1] = v.y;
        rb[q * 4 + 2] = v.z; rb[q * 4 + 3] = v.w;
    }

    float acc[MUL];
#pragma unroll
    for (int c = 0; c < MUL; ++c) acc[c] = br2[c];  // uniform -> s_load

    // 10 chunks of 10 hidden neurons (runtime loop keeps I-cache small)
    for (int ch = 0; ch < 10; ++ch) {
        float h[10];
#pragma unroll
        for (int jj = 0; jj < 10; ++jj) {
            int j = ch * 10 + jj;
            const float* wr = w1t + (size_t)j * NBc;  // uniform row
            float s = br1[j];
#pragma unroll
            for (int k = 0; k < NBc; ++k) s += rb[k] * wr[k];
            h[jj] = silu_f(s);
        }
#pragma unroll
        for (int jj = 0; jj < 10; ++jj) {
            int j = ch * 10 + jj;
            const float* w2 = Wr2 + (size_t)j * MUL;  // uniform row
            float hv = h[jj];
#pragma unroll
            for (int c = 0; c < MUL; ++c) acc[c] += hv * w2[c];
        }
    }

    float4* op = (float4*)(wout + (size_t)e * MUL);
#pragma unroll
    for (int q = 0; q < MUL / 4; ++q)
        op[q] = make_float4(acc[q * 4], acc[q * 4 + 1], acc[q * 4 + 2], acc[q * 4 + 3]);
}

// ---------------------------------------------------------------------------
// Gather/segment-sum: a[n][i][c] = (1/sqrt(K)) * sum_e sh[e][i]*s_src[e][c]*w[e][c]
// Wave per node, 4 waves/block, no barriers.
// ---------------------------------------------------------------------------
__global__ __launch_bounds__(256) void gather_kernel(
    const float* __restrict__ h_src, const int* __restrict__ off,
    const int* __restrict__ srcg, const float* __restrict__ sh,
    const float* __restrict__ wbuf, float* __restrict__ abuf, int n_out)
{
    int c = threadIdx.x & 63;
    int n = __builtin_amdgcn_readfirstlane(blockIdx.x * 4 + (threadIdx.x >> 6));
    if (n >= n_out) return;
    int e0 = off[n], e1 = off[n + 1];
    float acc[SH_DIM];
#pragma unroll
    for (int i = 0; i < SH_DIM; ++i) acc[i] = 0.0f;
    for (int p = e0; p < e1; ++p) {
        float wv = wbuf[(size_t)p * MUL + c];
        float s = h_src[(size_t)srcg[p] * FEAT + c];
        float sw = s * wv;
        const float* shp = sh + (size_t)p * SH_DIM;  // wave-uniform
#pragma unroll
        for (int i = 0; i < SH_DIM; ++i) acc[i] += shp[i] * sw;
    }
    const float isk = 0.22360679774997896f;  // 1/sqrt(20)
#pragma unroll
    for (int i = 0; i < SH_DIM; ++i)
        abuf[(size_t)n * FEAT + i * MUL + c] = acc[i] * isk;
}

// ---------------------------------------------------------------------------
// Per-l linear + gate + activation + residual. blockIdx.y: 0 -> l0+silu,
// 1 -> l1 (3 rows, gated), 2 -> l2 (5 rows, gated). Gate recomputed in y=1,2
// (no inter-block dependency). Weight columns in VGPRs, a-rows via s_load.
// ---------------------------------------------------------------------------
__global__ __launch_bounds__(256) void linear_kernel(
    const float* __restrict__ abuf, const float* __restrict__ base,
    float* __restrict__ outb,
    const float* __restrict__ Wl, const float* __restrict__ Wg, int n_out)
{
    int c = threadIdx.x & 63;
    int wid = __builtin_amdgcn_readfirstlane(blockIdx.x * 4 + (threadIdx.x >> 6));
    int nw = gridDim.x * 4;
    int y = blockIdx.y;

    if (y == 0) {
        float wl0[MUL];
#pragma unroll
        for (int k = 0; k < MUL; ++k) wl0[k] = Wl[k * MUL + c];
        for (int n = wid; n < n_out; n += nw) {
            const float* ar = abuf + (size_t)n * FEAT;  // row i=0, uniform
            float u = 0.0f;
#pragma unroll
            for (int k = 0; k < MUL; ++k) u += ar[k] * wl0[k];
            size_t idx = (size_t)n * FEAT + c;
            outb[idx] = base[idx] + silu_f(u);
        }
    } else {
        int ibase = (y == 1) ? 1 : 4;
        int ni = (y == 1) ? 3 : 5;
        const float* W = Wl + (size_t)y * MUL * MUL;
        float wcol[MUL], wg[MUL];
#pragma unroll
        for (int k = 0; k < MUL; ++k) { wcol[k] = W[k * MUL + c]; wg[k] = Wg[k * MUL + c]; }
        for (int n = wid; n < n_out; n += nw) {
            const float* a0 = abuf + (size_t)n * FEAT;  // row 0 for gate
            float g = 0.0f;
#pragma unroll
            for (int k = 0; k < MUL; ++k) g += a0[k] * wg[k];
            g = sigmoid_f(g);
            for (int ii = 0; ii < ni; ++ii) {
                const float* ar = a0 + (size_t)(ibase + ii) * MUL;
                float u = 0.0f;
#pragma unroll
                for (int k = 0; k < MUL; ++k) u += ar[k] * wcol[k];
                size_t idx = (size_t)n * FEAT + (size_t)(ibase + ii) * MUL + c;
                outb[idx] = base[idx] + u * g;
            }
        }
    }
}

// ---------------------------------------------------------------------------
// Readout: out[n] = dot(p[n,0,:], W_out[:,0])
// ---------------------------------------------------------------------------
__global__ __launch_bounds__(64) void out_kernel(const float* __restrict__ p,
                                                 const float* __restrict__ Wout,
                                                 float* __restrict__ out)
{
    int n = blockIdx.x;
    int c = threadIdx.x;
    float v = p[(size_t)n * FEAT + c] * Wout[c];
#pragma unroll
    for (int o = 32; o > 0; o >>= 1) v += __shfl_down(v, o, 64);
    if (c == 0) out[n] = v;
}

// ---------------------------------------------------------------------------
extern "C" void kernel_launch(void* const* d_in, const int* in_sizes, int n_in,
                              void* d_out, int out_size, void* d_ws, size_t ws_size,
                              hipStream_t stream)
{
    const float* atom_xyz  = (const float*)d_in[0];
    const float* a_disp    = (const float*)d_in[1];
    const float* cell      = (const float*)d_in[2];
    const float* probe_xyz = (const float*)d_in[3];
    const float* p_disp    = (const float*)d_in[4];
    const float* W_embed   = (const float*)d_in[5];
    const float* Wr1       = (const float*)d_in[6];
    const float* br1       = (const float*)d_in[7];
    const float* Wr2       = (const float*)d_in[8];
    const float* br2       = (const float*)d_in[9];
    const float* Wl        = (const float*)d_in[10];
    const float* Wg        = (const float*)d_in[11];
    const float* pWr1      = (const float*)d_in[12];
    const float* pbr1      = (const float*)d_in[13];
    const float* pWr2      = (const float*)d_in[14];
    const float* pbr2      = (const float*)d_in[15];
    const float* pWl       = (const float*)d_in[16];
    const float* pWg       = (const float*)d_in[17];
    const float* W_out     = (const float*)d_in[18];
    const int*   atom_edges  = (const int*)d_in[19];
    const int*   probe_edges = (const int*)d_in[20];
    const int*   nodes       = (const int*)d_in[21];
    float* out = (float*)d_out;

    char* w = (char*)d_ws;
    auto alloc = [&](size_t bytes) -> void* {
        void* r = (void*)w;
        w += (bytes + 255) & ~(size_t)255;
        return r;
    };
    float* sh_a   = (float*)alloc((size_t)ET * 9 * 4);
    float* rbf_a  = (float*)alloc((size_t)ET * 20 * 4);
    int*   src_a  = (int*)alloc((size_t)ET * 4);
    int*   cnt_a  = (int*)alloc((size_t)NA * 4);
    int*   off_a  = (int*)alloc((size_t)(NA + 1) * 4);
    int*   cur_a  = (int*)alloc((size_t)NA * 4);
    float* sh_p   = (float*)alloc((size_t)PET * 9 * 4);
    float* rbf_p  = (float*)alloc((size_t)PET * 20 * 4);
    int*   src_p  = (int*)alloc((size_t)PET * 4);
    int*   cnt_p  = (int*)alloc((size_t)NP * 4);
    int*   off_p  = (int*)alloc((size_t)(NP + 1) * 4);
    int*   cur_p  = (int*)alloc((size_t)NP * 4);
    float* h0     = (float*)alloc((size_t)NA * FEAT * 4);
    float* rep0   = (float*)alloc((size_t)NA * FEAT * 4);
    float* rep1   = (float*)alloc((size_t)NA * FEAT * 4);
    float* rep2   = (float*)alloc((size_t)NA * FEAT * 4);
    float* pbuf   = (float*)alloc((size_t)NP * FEAT * 4);
    float* abuf   = (float*)alloc((size_t)NP * FEAT * 4);
    float* wbuf   = (float*)alloc((size_t)PET * MUL * 4);
    float* w1t    = (float*)alloc((size_t)6 * HID * NBc * 4);

    hipMemsetAsync(cnt_a, 0, (size_t)NA * 4, stream);
    hipMemsetAsync(cnt_p, 0, (size_t)NP * 4, stream);
    hipMemsetAsync(pbuf, 0, (size_t)NP * FEAT * 4, stream);

    // CSR build + geometry in CSR order
    count_kernel<<<(ET + 255) / 256, 256, 0, stream>>>(atom_edges, cnt_a, Ec, ET, Nc);
    count_kernel<<<(PET + 255) / 256, 256, 0, stream>>>(probe_edges, cnt_p, PEc, PET, Pc);
    scan_kernel<<<1, 256, 0, stream>>>(cnt_a, off_a, cur_a, NA);
    scan_kernel<<<1, 256, 0, stream>>>(cnt_p, off_p, cur_p, NP);
    geom_kernel<<<(ET + 255) / 256, 256, 0, stream>>>(
        atom_xyz, atom_xyz, atom_edges, a_disp, cell, cur_a,
        sh_a, rbf_a, src_a, Ec, ET, Nc, Nc);
    geom_kernel<<<(PET + 255) / 256, 256, 0, stream>>>(
        atom_xyz, probe_xyz, probe_edges, p_disp, cell, cur_p,
        sh_p, rbf_p, src_p, PEc, PET, Nc, Pc);

    transpose_w1_kernel<<<(6 * HID * NBc + 255) / 256, 256, 0, stream>>>(Wr1, pWr1, w1t);
    embed_kernel<<<(NA * FEAT + 255) / 256, 256, 0, stream>>>(nodes, W_embed, h0);

    const float* hprev = h0;
    float* reps[3] = {rep0, rep1, rep2};
    dim3 lingrid(128, 3);

    // atom layers
    for (int t = 0; t < Tc; ++t) {
        mlp_kernel<<<ET / 64, 64, 0, stream>>>(
            rbf_a, w1t + (size_t)t * HID * NBc, br1 + (size_t)t * HID,
            Wr2 + (size_t)t * HID * MUL, br2 + (size_t)t * MUL, wbuf, ET);
        gather_kernel<<<NA / 4, 256, 0, stream>>>(hprev, off_a, src_a, sh_a, wbuf, abuf, NA);
        linear_kernel<<<lingrid, 256, 0, stream>>>(
            abuf, hprev, reps[t],
            Wl + (size_t)t * 3 * MUL * MUL, Wg + (size_t)t * MUL * MUL, NA);
        hprev = reps[t];
    }

    // probe layers (accumulate into pbuf)
    for (int t = 0; t < Tc; ++t) {
        mlp_kernel<<<PET / 64, 64, 0, stream>>>(
            rbf_p, w1t + (size_t)(3 + t) * HID * NBc, pbr1 + (size_t)t * HID,
            pWr2 + (size_t)t * HID * MUL, pbr2 + (size_t)t * MUL, wbuf, PET);
        gather_kernel<<<NP / 4, 256, 0, stream>>>(reps[t], off_p, src_p, sh_p, wbuf, abuf, NP);
        linear_kernel<<<lingrid, 256, 0, stream>>>(
            abuf, pbuf, pbuf,
            pWl + (size_t)t * 3 * MUL * MUL, pWg + (size_t)t * MUL * MUL, NP);
    }

    out_kernel<<<NP, 64, 0, stream>>>(pbuf, W_out, out);
}

// Round 4
// 562.551 us; speedup vs baseline: 1.6656x; 1.2336x over previous
//
#include <hip/hip_runtime.h>
#include <math.h>

#define Bc 4
#define Nc 512
#define Pc 1024
#define Kc 20
#define SH_DIM 9
#define MUL 64
#define NBc 20
#define HID 100
#define Tc 3
#define CUTc 4.0f
#define Ec (Nc * Kc)        /* 10240 */
#define PEc (Pc * Kc)       /* 20480 */
#define NA (Bc * Nc)        /* 2048 */
#define NP (Bc * Pc)        /* 4096 */
#define ET (Bc * Ec)        /* 40960 */
#define PET (Bc * PEc)      /* 81920 */
#define FEAT (SH_DIM * MUL) /* 576 */

__device__ __forceinline__ float silu_f(float x) { return x / (1.0f + __expf(-x)); }
__device__ __forceinline__ float sigmoid_f(float x) { return 1.0f / (1.0f + __expf(-x)); }

// ---------------------------------------------------------------------------
// Pass 1: count edges per destination
// ---------------------------------------------------------------------------
__global__ void count_kernel(const int* __restrict__ edges, int* __restrict__ cnt,
                             int Eper, int Etot, int dst_stride)
{
    int e = blockIdx.x * blockDim.x + threadIdx.x;
    if (e >= Etot) return;
    int b = e / Eper;
    atomicAdd(&cnt[edges[e * 2 + 1] + b * dst_stride], 1);
}

// ---------------------------------------------------------------------------
// Single-block exclusive scan: off[0..n] plus cursor copy
// ---------------------------------------------------------------------------
__global__ void scan_kernel(const int* __restrict__ cnt, int* __restrict__ off,
                            int* __restrict__ cur, int n)
{
    __shared__ int part[256];
    int t = threadIdx.x;
    int per = (n + 255) / 256;
    int lo = t * per, hi = min(lo + per, n);
    int s = 0;
    for (int i = lo; i < hi; ++i) s += cnt[i];
    part[t] = s;
    __syncthreads();
    if (t == 0) {
        int run = 0;
        for (int i = 0; i < 256; ++i) { int v = part[i]; part[i] = run; run += v; }
        off[n] = run;
    }
    __syncthreads();
    int run = part[t];
    for (int i = lo; i < hi; ++i) { off[i] = run; cur[i] = run; run += cnt[i]; }
}

// ---------------------------------------------------------------------------
// Pass 2: geometry, written directly in CSR (dst-sorted) order
// ---------------------------------------------------------------------------
__global__ void geom_kernel(const float* __restrict__ pos_src,
                            const float* __restrict__ pos_dst,
                            const int*   __restrict__ edges,
                            const float* __restrict__ displ,
                            const float* __restrict__ cell,
                            int* __restrict__ cur,
                            float* __restrict__ sh_out,   // (Etot,9)  CSR order
                            float* __restrict__ rbf_out,  // (Etot,20) CSR order
                            int*   __restrict__ src_out,  // (Etot)    CSR order
                            int Eper, int Etot, int src_stride, int dst_stride)
{
    int e = blockIdx.x * blockDim.x + threadIdx.x;
    if (e >= Etot) return;
    int b = e / Eper;
    int sg = edges[e * 2 + 0] + b * src_stride;
    int dg = edges[e * 2 + 1] + b * dst_stride;
    const float* C = cell + b * 9;
    float d0 = displ[e * 3 + 0], d1 = displ[e * 3 + 1], d2 = displ[e * 3 + 2];
    float dx = d0 * C[0] + d1 * C[3] + d2 * C[6];
    float dy = d0 * C[1] + d1 * C[4] + d2 * C[7];
    float dz = d0 * C[2] + d1 * C[5] + d2 * C[8];
    float vx = pos_dst[dg * 3 + 0] - (pos_src[sg * 3 + 0] + dx);
    float vy = pos_dst[dg * 3 + 1] - (pos_src[sg * 3 + 1] + dy);
    float vz = pos_dst[dg * 3 + 2] - (pos_src[sg * 3 + 2] + dz);
    float r = sqrtf(vx * vx + vy * vy + vz * vz);
    float inv = 1.0f / fmaxf(r, 1e-9f);
    float x = vx * inv, y = vy * inv, z = vz * inv;
    const float s3 = 1.7320508075688772f;
    const float s5 = 2.23606797749979f;
    const float s15 = 3.872983346207417f;
    int pos = atomicAdd(&cur[dg], 1);
    float* sh = sh_out + (size_t)pos * 9;
    sh[0] = 1.0f;
    sh[1] = s3 * x;
    sh[2] = s3 * y;
    sh[3] = s3 * z;
    sh[4] = s15 * x * y;
    sh[5] = s15 * y * z;
    sh[6] = 0.5f * s5 * (3.0f * z * z - 1.0f);
    sh[7] = s15 * x * z;
    sh[8] = 0.5f * s15 * (x * x - y * y);
    const float step = CUTc / (NBc - 1);
    const float inv_sigma = (float)NBc / CUTc;
    float* rb = rbf_out + (size_t)pos * 20;
#pragma unroll
    for (int k = 0; k < NBc; ++k) {
        float t = (r - k * step) * inv_sigma;
        rb[k] = __expf(-t * t);
    }
    src_out[pos] = sg;
}

// ---------------------------------------------------------------------------
// W1 transpose: w1t_all[t6][j][k] = W1[t6][k][j]  (t6: 0-2 atom, 3-5 probe)
// ---------------------------------------------------------------------------
__global__ void transpose_w1_kernel(const float* __restrict__ Wr1,
                                    const float* __restrict__ pWr1,
                                    float* __restrict__ w1t_all)
{
    int idx = blockIdx.x * 256 + threadIdx.x;
    if (idx >= 6 * HID * NBc) return;
    int t6 = idx / (HID * NBc);
    int rem = idx % (HID * NBc);
    int j = rem / NBc;
    int k = rem % NBc;
    const float* src = (t6 < 3) ? (Wr1 + (size_t)t6 * NBc * HID)
                                : (pWr1 + (size_t)(t6 - 3) * NBc * HID);
    w1t_all[idx] = src[k * HID + j];
}

// ---------------------------------------------------------------------------
// Embedding
// ---------------------------------------------------------------------------
__global__ void embed_kernel(const int* __restrict__ nodes, const float* __restrict__ Wemb,
                             float* __restrict__ h0)
{
    int idx = blockIdx.x * blockDim.x + threadIdx.x;
    if (idx >= NA * FEAT) return;
    int a = idx / FEAT;
    int r = idx % FEAT;
    int i = r / MUL;
    int c = r % MUL;
    h0[idx] = (i == 0) ? Wemb[nodes[a] * MUL + c] : 0.0f;
}

// ---------------------------------------------------------------------------
// Edge radial MLP. Block = 256 threads = 4 waves, all covering the SAME
// 64-edge group; wave q computes output channels [16q, 16q+16). Lane = edge.
// Weights are wave-uniform -> SGPR operands; hidden recomputed per quarter
// (1.7x FLOPs for 4x waves -> latency hiding; round-3 had 1.25 waves/SIMD
// and 22% VALUBusy).
// ---------------------------------------------------------------------------
__global__ __launch_bounds__(256) void mlp_kernel(
    const float* __restrict__ rbf,    // (Etot,20) CSR order
    const float* __restrict__ w1t,    // (100,20) transposed layer slice
    const float* __restrict__ br1,    // (100)
    const float* __restrict__ Wr2,    // (100,64)
    const float* __restrict__ br2,    // (64)
    float* __restrict__ wout,         // (Etot,64)
    int Etot)
{
    int lane = threadIdx.x & 63;
    int q = __builtin_amdgcn_readfirstlane(threadIdx.x >> 6);  // quarter, uniform
    int e = blockIdx.x * 64 + lane;
    if (e >= Etot) return;

    float rb[NBc];
    const float4* rp = (const float4*)(rbf + (size_t)e * NBc);
#pragma unroll
    for (int i = 0; i < NBc / 4; ++i) {
        float4 v = rp[i];
        rb[i * 4 + 0] = v.x; rb[i * 4 + 1] = v.y;
        rb[i * 4 + 2] = v.z; rb[i * 4 + 3] = v.w;
    }

    const float* w2q = Wr2 + q * 16;   // uniform column-block base
    const float* b2q = br2 + q * 16;
    float acc[16];
#pragma unroll
    for (int cc = 0; cc < 16; ++cc) acc[cc] = b2q[cc];

    for (int ch = 0; ch < 10; ++ch) {  // 10 hidden neurons per chunk
        float h[10];
#pragma unroll
        for (int jj = 0; jj < 10; ++jj) {
            int j = ch * 10 + jj;
            const float* wr = w1t + (size_t)j * NBc;  // uniform row
            float s = br1[j];
#pragma unroll
            for (int k = 0; k < NBc; ++k) s += rb[k] * wr[k];
            h[jj] = silu_f(s);
        }
#pragma unroll
        for (int jj = 0; jj < 10; ++jj) {
            int j = ch * 10 + jj;
            const float* w2 = w2q + (size_t)j * MUL;  // uniform row slice
            float hv = h[jj];
#pragma unroll
            for (int cc = 0; cc < 16; ++cc) acc[cc] += hv * w2[cc];
        }
    }

    float4* op = (float4*)(wout + (size_t)e * MUL + q * 16);
#pragma unroll
    for (int i = 0; i < 4; ++i)
        op[i] = make_float4(acc[i * 4], acc[i * 4 + 1], acc[i * 4 + 2], acc[i * 4 + 3]);
}

// ---------------------------------------------------------------------------
// Gather/segment-sum: a[n][i][c] = (1/sqrt(K)) * sum_e sh[e][i]*s_src[e][c]*w[e][c]
// Wave per node, 4 waves/block, no barriers.
// ---------------------------------------------------------------------------
__global__ __launch_bounds__(256) void gather_kernel(
    const float* __restrict__ h_src, const int* __restrict__ off,
    const int* __restrict__ srcg, const float* __restrict__ sh,
    const float* __restrict__ wbuf, float* __restrict__ abuf, int n_out)
{
    int c = threadIdx.x & 63;
    int n = __builtin_amdgcn_readfirstlane(blockIdx.x * 4 + (threadIdx.x >> 6));
    if (n >= n_out) return;
    int e0 = off[n], e1 = off[n + 1];
    float acc[SH_DIM];
#pragma unroll
    for (int i = 0; i < SH_DIM; ++i) acc[i] = 0.0f;
    for (int p = e0; p < e1; ++p) {
        float wv = wbuf[(size_t)p * MUL + c];
        float s = h_src[(size_t)srcg[p] * FEAT + c];
        float sw = s * wv;
        const float* shp = sh + (size_t)p * SH_DIM;  // wave-uniform
#pragma unroll
        for (int i = 0; i < SH_DIM; ++i) acc[i] += shp[i] * sw;
    }
    const float isk = 0.22360679774997896f;  // 1/sqrt(20)
#pragma unroll
    for (int i = 0; i < SH_DIM; ++i)
        abuf[(size_t)n * FEAT + i * MUL + c] = acc[i] * isk;
}

// ---------------------------------------------------------------------------
// Per-l linear + gate + activation + residual. blockIdx.y: 0 -> l0+silu,
// 1 -> l1 (3 rows, gated), 2 -> l2 (5 rows, gated). Gate recomputed in y=1,2.
// ---------------------------------------------------------------------------
__global__ __launch_bounds__(256) void linear_kernel(
    const float* __restrict__ abuf, const float* __restrict__ base,
    float* __restrict__ outb,
    const float* __restrict__ Wl, const float* __restrict__ Wg, int n_out)
{
    int c = threadIdx.x & 63;
    int wid = __builtin_amdgcn_readfirstlane(blockIdx.x * 4 + (threadIdx.x >> 6));
    int nw = gridDim.x * 4;
    int y = blockIdx.y;

    if (y == 0) {
        float wl0[MUL];
#pragma unroll
        for (int k = 0; k < MUL; ++k) wl0[k] = Wl[k * MUL + c];
        for (int n = wid; n < n_out; n += nw) {
            const float* ar = abuf + (size_t)n * FEAT;  // row i=0, uniform
            float u = 0.0f;
#pragma unroll
            for (int k = 0; k < MUL; ++k) u += ar[k] * wl0[k];
            size_t idx = (size_t)n * FEAT + c;
            outb[idx] = base[idx] + silu_f(u);
        }
    } else {
        int ibase = (y == 1) ? 1 : 4;
        int ni = (y == 1) ? 3 : 5;
        const float* W = Wl + (size_t)y * MUL * MUL;
        float wcol[MUL], wg[MUL];
#pragma unroll
        for (int k = 0; k < MUL; ++k) { wcol[k] = W[k * MUL + c]; wg[k] = Wg[k * MUL + c]; }
        for (int n = wid; n < n_out; n += nw) {
            const float* a0 = abuf + (size_t)n * FEAT;  // row 0 for gate
            float g = 0.0f;
#pragma unroll
            for (int k = 0; k < MUL; ++k) g += a0[k] * wg[k];
            g = sigmoid_f(g);
            for (int ii = 0; ii < ni; ++ii) {
                const float* ar = a0 + (size_t)(ibase + ii) * MUL;
                float u = 0.0f;
#pragma unroll
                for (int k = 0; k < MUL; ++k) u += ar[k] * wcol[k];
                size_t idx = (size_t)n * FEAT + (size_t)(ibase + ii) * MUL + c;
                outb[idx] = base[idx] + u * g;
            }
        }
    }
}

// ---------------------------------------------------------------------------
// Readout: out[n] = dot(p[n,0,:], W_out[:,0])
// ---------------------------------------------------------------------------
__global__ __launch_bounds__(64) void out_kernel(const float* __restrict__ p,
                                                 const float* __restrict__ Wout,
                                                 float* __restrict__ out)
{
    int n = blockIdx.x;
    int c = threadIdx.x;
    float v = p[(size_t)n * FEAT + c] * Wout[c];
#pragma unroll
    for (int o = 32; o > 0; o >>= 1) v += __shfl_down(v, o, 64);
    if (c == 0) out[n] = v;
}

// ---------------------------------------------------------------------------
extern "C" void kernel_launch(void* const* d_in, const int* in_sizes, int n_in,
                              void* d_out, int out_size, void* d_ws, size_t ws_size,
                              hipStream_t stream)
{
    const float* atom_xyz  = (const float*)d_in[0];
    const float* a_disp    = (const float*)d_in[1];
    const float* cell      = (const float*)d_in[2];
    const float* probe_xyz = (const float*)d_in[3];
    const float* p_disp    = (const float*)d_in[4];
    const float* W_embed   = (const float*)d_in[5];
    const float* Wr1       = (const float*)d_in[6];
    const float* br1       = (const float*)d_in[7];
    const float* Wr2       = (const float*)d_in[8];
    const float* br2       = (const float*)d_in[9];
    const float* Wl        = (const float*)d_in[10];
    const float* Wg        = (const float*)d_in[11];
    const float* pWr1      = (const float*)d_in[12];
    const float* pbr1      = (const float*)d_in[13];
    const float* pWr2      = (const float*)d_in[14];
    const float* pbr2      = (const float*)d_in[15];
    const float* pWl       = (const float*)d_in[16];
    const float* pWg       = (const float*)d_in[17];
    const float* W_out     = (const float*)d_in[18];
    const int*   atom_edges  = (const int*)d_in[19];
    const int*   probe_edges = (const int*)d_in[20];
    const int*   nodes       = (const int*)d_in[21];
    float* out = (float*)d_out;

    char* w = (char*)d_ws;
    auto alloc = [&](size_t bytes) -> void* {
        void* r = (void*)w;
        w += (bytes + 255) & ~(size_t)255;
        return r;
    };
    float* sh_a   = (float*)alloc((size_t)ET * 9 * 4);
    float* rbf_a  = (float*)alloc((size_t)ET * 20 * 4);
    int*   src_a  = (int*)alloc((size_t)ET * 4);
    int*   cnt_a  = (int*)alloc((size_t)NA * 4);
    int*   off_a  = (int*)alloc((size_t)(NA + 1) * 4);
    int*   cur_a  = (int*)alloc((size_t)NA * 4);
    float* sh_p   = (float*)alloc((size_t)PET * 9 * 4);
    float* rbf_p  = (float*)alloc((size_t)PET * 20 * 4);
    int*   src_p  = (int*)alloc((size_t)PET * 4);
    int*   cnt_p  = (int*)alloc((size_t)NP * 4);
    int*   off_p  = (int*)alloc((size_t)(NP + 1) * 4);
    int*   cur_p  = (int*)alloc((size_t)NP * 4);
    float* h0     = (float*)alloc((size_t)NA * FEAT * 4);
    float* rep0   = (float*)alloc((size_t)NA * FEAT * 4);
    float* rep1   = (float*)alloc((size_t)NA * FEAT * 4);
    float* rep2   = (float*)alloc((size_t)NA * FEAT * 4);
    float* pbuf   = (float*)alloc((size_t)NP * FEAT * 4);
    float* abuf   = (float*)alloc((size_t)NP * FEAT * 4);
    float* wbuf   = (float*)alloc((size_t)PET * MUL * 4);
    float* w1t    = (float*)alloc((size_t)6 * HID * NBc * 4);

    hipMemsetAsync(cnt_a, 0, (size_t)NA * 4, stream);
    hipMemsetAsync(cnt_p, 0, (size_t)NP * 4, stream);
    hipMemsetAsync(pbuf, 0, (size_t)NP * FEAT * 4, stream);

    // CSR build + geometry in CSR order
    count_kernel<<<(ET + 255) / 256, 256, 0, stream>>>(atom_edges, cnt_a, Ec, ET, Nc);
    count_kernel<<<(PET + 255) / 256, 256, 0, stream>>>(probe_edges, cnt_p, PEc, PET, Pc);
    scan_kernel<<<1, 256, 0, stream>>>(cnt_a, off_a, cur_a, NA);
    scan_kernel<<<1, 256, 0, stream>>>(cnt_p, off_p, cur_p, NP);
    geom_kernel<<<(ET + 255) / 256, 256, 0, stream>>>(
        atom_xyz, atom_xyz, atom_edges, a_disp, cell, cur_a,
        sh_a, rbf_a, src_a, Ec, ET, Nc, Nc);
    geom_kernel<<<(PET + 255) / 256, 256, 0, stream>>>(
        atom_xyz, probe_xyz, probe_edges, p_disp, cell, cur_p,
        sh_p, rbf_p, src_p, PEc, PET, Nc, Pc);

    transpose_w1_kernel<<<(6 * HID * NBc + 255) / 256, 256, 0, stream>>>(Wr1, pWr1, w1t);
    embed_kernel<<<(NA * FEAT + 255) / 256, 256, 0, stream>>>(nodes, W_embed, h0);

    const float* hprev = h0;
    float* reps[3] = {rep0, rep1, rep2};
    dim3 lingrid(128, 3);

    // atom layers
    for (int t = 0; t < Tc; ++t) {
        mlp_kernel<<<ET / 64, 256, 0, stream>>>(
            rbf_a, w1t + (size_t)t * HID * NBc, br1 + (size_t)t * HID,
            Wr2 + (size_t)t * HID * MUL, br2 + (size_t)t * MUL, wbuf, ET);
        gather_kernel<<<NA / 4, 256, 0, stream>>>(hprev, off_a, src_a, sh_a, wbuf, abuf, NA);
        linear_kernel<<<lingrid, 256, 0, stream>>>(
            abuf, hprev, reps[t],
            Wl + (size_t)t * 3 * MUL * MUL, Wg + (size_t)t * MUL * MUL, NA);
        hprev = reps[t];
    }

    // probe layers (accumulate into pbuf)
    for (int t = 0; t < Tc; ++t) {
        mlp_kernel<<<PET / 64, 256, 0, stream>>>(
            rbf_p, w1t + (size_t)(3 + t) * HID * NBc, pbr1 + (size_t)t * HID,
            pWr2 + (size_t)t * HID * MUL, pbr2 + (size_t)t * MUL, wbuf, PET);
        gather_kernel<<<NP / 4, 256, 0, stream>>>(reps[t], off_p, src_p, sh_p, wbuf, abuf, NP);
        linear_kernel<<<lingrid, 256, 0, stream>>>(
            abuf, pbuf, pbuf,
            pWl + (size_t)t * 3 * MUL * MUL, pWg + (size_t)t * MUL * MUL, NP);
    }

    out_kernel<<<NP, 64, 0, stream>>>(pbuf, W_out, out);
}

// Round 5
// 270.836 us; speedup vs baseline: 3.4595x; 2.0771x over previous
//
#include <hip/hip_runtime.h>
#include <math.h>

#define Bc 4
#define Nc 512
#define Pc 1024
#define Kc 20
#define SH_DIM 9
#define MUL 64
#define NBc 20
#define HID 100
#define Tc 3
#define CUTc 4.0f
#define Ec (Nc * Kc)        /* 10240 */
#define PEc (Pc * Kc)       /* 20480 */
#define NA (Bc * Nc)        /* 2048 */
#define NP (Bc * Pc)        /* 4096 */
#define ET (Bc * Ec)        /* 40960 */
#define PET (Bc * PEc)      /* 81920 */
#define FEAT (SH_DIM * MUL) /* 576 */
#define TBL 8192            /* w-table points; r in [0, RMAXT], rmax = 16*sqrt(3) = 27.71 */
#define RMAXT 28.0f

__device__ __forceinline__ float silu_f(float x) { return x / (1.0f + __expf(-x)); }
__device__ __forceinline__ float sigmoid_f(float x) { return 1.0f / (1.0f + __expf(-x)); }

// ---------------------------------------------------------------------------
// Pass 1: count edges per destination
// ---------------------------------------------------------------------------
__global__ void count_kernel(const int* __restrict__ edges, int* __restrict__ cnt,
                             int Eper, int Etot, int dst_stride)
{
    int e = blockIdx.x * blockDim.x + threadIdx.x;
    if (e >= Etot) return;
    int b = e / Eper;
    atomicAdd(&cnt[edges[e * 2 + 1] + b * dst_stride], 1);
}

// ---------------------------------------------------------------------------
// Single-block exclusive scan: off[0..n] plus cursor copy
// ---------------------------------------------------------------------------
__global__ void scan_kernel(const int* __restrict__ cnt, int* __restrict__ off,
                            int* __restrict__ cur, int n)
{
    __shared__ int part[256];
    int t = threadIdx.x;
    int per = (n + 255) / 256;
    int lo = t * per, hi = min(lo + per, n);
    int s = 0;
    for (int i = lo; i < hi; ++i) s += cnt[i];
    part[t] = s;
    __syncthreads();
    if (t == 0) {
        int run = 0;
        for (int i = 0; i < 256; ++i) { int v = part[i]; part[i] = run; run += v; }
        off[n] = run;
    }
    __syncthreads();
    int run = part[t];
    for (int i = lo; i < hi; ++i) { off[i] = run; cur[i] = run; run += cnt[i]; }
}

// ---------------------------------------------------------------------------
// Pass 2: geometry in CSR (dst-sorted) order: sh[9] + r per edge (no rbf)
// ---------------------------------------------------------------------------
__global__ void geom_kernel(const float* __restrict__ pos_src,
                            const float* __restrict__ pos_dst,
                            const int*   __restrict__ edges,
                            const float* __restrict__ displ,
                            const float* __restrict__ cell,
                            int* __restrict__ cur,
                            float* __restrict__ sh_out,   // (Etot,9)  CSR order
                            float* __restrict__ r_out,    // (Etot)    CSR order
                            int*   __restrict__ src_out,  // (Etot)    CSR order
                            int Eper, int Etot, int src_stride, int dst_stride)
{
    int e = blockIdx.x * blockDim.x + threadIdx.x;
    if (e >= Etot) return;
    int b = e / Eper;
    int sg = edges[e * 2 + 0] + b * src_stride;
    int dg = edges[e * 2 + 1] + b * dst_stride;
    const float* C = cell + b * 9;
    float d0 = displ[e * 3 + 0], d1 = displ[e * 3 + 1], d2 = displ[e * 3 + 2];
    float dx = d0 * C[0] + d1 * C[3] + d2 * C[6];
    float dy = d0 * C[1] + d1 * C[4] + d2 * C[7];
    float dz = d0 * C[2] + d1 * C[5] + d2 * C[8];
    float vx = pos_dst[dg * 3 + 0] - (pos_src[sg * 3 + 0] + dx);
    float vy = pos_dst[dg * 3 + 1] - (pos_src[sg * 3 + 1] + dy);
    float vz = pos_dst[dg * 3 + 2] - (pos_src[sg * 3 + 2] + dz);
    float r = sqrtf(vx * vx + vy * vy + vz * vz);
    float inv = 1.0f / fmaxf(r, 1e-9f);
    float x = vx * inv, y = vy * inv, z = vz * inv;
    const float s3 = 1.7320508075688772f;
    const float s5 = 2.23606797749979f;
    const float s15 = 3.872983346207417f;
    int pos = atomicAdd(&cur[dg], 1);
    float* sh = sh_out + (size_t)pos * 9;
    sh[0] = 1.0f;
    sh[1] = s3 * x;
    sh[2] = s3 * y;
    sh[3] = s3 * z;
    sh[4] = s15 * x * y;
    sh[5] = s15 * y * z;
    sh[6] = 0.5f * s5 * (3.0f * z * z - 1.0f);
    sh[7] = s15 * x * z;
    sh[8] = 0.5f * s15 * (x * x - y * y);
    r_out[pos] = r;
    src_out[pos] = sg;
}

// ---------------------------------------------------------------------------
// W1 transpose: w1t_all[t6][j][k] = W1[t6][k][j]  (t6: 0-2 atom, 3-5 probe)
// ---------------------------------------------------------------------------
__global__ void transpose_w1_kernel(const float* __restrict__ Wr1,
                                    const float* __restrict__ pWr1,
                                    float* __restrict__ w1t_all)
{
    int idx = blockIdx.x * 256 + threadIdx.x;
    if (idx >= 6 * HID * NBc) return;
    int t6 = idx / (HID * NBc);
    int rem = idx % (HID * NBc);
    int j = rem / NBc;
    int k = rem % NBc;
    const float* src = (t6 < 3) ? (Wr1 + (size_t)t6 * NBc * HID)
                                : (pWr1 + (size_t)(t6 - 3) * NBc * HID);
    w1t_all[idx] = src[k * HID + j];
}

// ---------------------------------------------------------------------------
// Embedding
// ---------------------------------------------------------------------------
__global__ void embed_kernel(const int* __restrict__ nodes, const float* __restrict__ Wemb,
                             float* __restrict__ h0)
{
    int idx = blockIdx.x * blockDim.x + threadIdx.x;
    if (idx >= NA * FEAT) return;
    int a = idx / FEAT;
    int r = idx % FEAT;
    int i = r / MUL;
    int c = r % MUL;
    h0[idx] = (i == 0) ? Wemb[nodes[a] * MUL + c] : 0.0f;
}

// ---------------------------------------------------------------------------
// Radial-MLP table: wtab[ly][i][c] = MLP_ly(rbf(r_i)), r_i = i*RMAXT/TBL,
// for all 6 layer-weight-sets in one launch (ly 0-2 atom, 3-5 probe).
// Block = 4 waves on same 64 grid points; wave q -> channels [16q,16q+16).
// Weights consumed as wave-uniform scalar operands (round-4 structure).
// ---------------------------------------------------------------------------
__global__ __launch_bounds__(256) void table_kernel(
    const float* __restrict__ w1t,   // (6,100,20) transposed
    const float* __restrict__ br1,  const float* __restrict__ pbr1,
    const float* __restrict__ Wr2,  const float* __restrict__ pWr2,
    const float* __restrict__ br2,  const float* __restrict__ pbr2,
    float* __restrict__ wtab)        // (6, TBL, 64)
{
    int lane = threadIdx.x & 63;
    int q = __builtin_amdgcn_readfirstlane(threadIdx.x >> 6);
    int g = blockIdx.x;
    int ly = g / (TBL / 64);
    int grp = g % (TBL / 64);
    int t3 = (ly < 3) ? ly : ly - 3;
    const float* w1 = w1t + (size_t)ly * HID * NBc;
    const float* b1 = ((ly < 3) ? br1 : pbr1) + (size_t)t3 * HID;
    const float* w2 = ((ly < 3) ? Wr2 : pWr2) + (size_t)t3 * HID * MUL;
    const float* b2 = ((ly < 3) ? br2 : pbr2) + (size_t)t3 * MUL;

    int i = grp * 64 + lane;
    float r = (float)i * (RMAXT / (float)TBL);
    float rb[NBc];
    const float step = CUTc / (NBc - 1);
    const float inv_sigma = (float)NBc / CUTc;
#pragma unroll
    for (int k = 0; k < NBc; ++k) {
        float t = (r - k * step) * inv_sigma;
        rb[k] = __expf(-t * t);
    }

    const float* w2q = w2 + q * 16;
    float acc[16];
#pragma unroll
    for (int cc = 0; cc < 16; ++cc) acc[cc] = b2[q * 16 + cc];

    for (int ch = 0; ch < 10; ++ch) {
        float h[10];
#pragma unroll
        for (int jj = 0; jj < 10; ++jj) {
            int j = ch * 10 + jj;
            const float* wr = w1 + (size_t)j * NBc;  // uniform row
            float s = b1[j];
#pragma unroll
            for (int k = 0; k < NBc; ++k) s += rb[k] * wr[k];
            h[jj] = silu_f(s);
        }
#pragma unroll
        for (int jj = 0; jj < 10; ++jj) {
            int j = ch * 10 + jj;
            const float* w2r = w2q + (size_t)j * MUL;  // uniform row slice
            float hv = h[jj];
#pragma unroll
            for (int cc = 0; cc < 16; ++cc) acc[cc] += hv * w2r[cc];
        }
    }

    float4* op = (float4*)(wtab + ((size_t)ly * TBL + i) * MUL + q * 16);
#pragma unroll
    for (int v = 0; v < 4; ++v)
        op[v] = make_float4(acc[v * 4], acc[v * 4 + 1], acc[v * 4 + 2], acc[v * 4 + 3]);
}

// ---------------------------------------------------------------------------
// Gather/segment-sum with in-loop table lerp:
// a[n][i][c] = (1/sqrt(K)) * sum_e sh[e][i] * s_src[e][c] * lerp(wtab, r_e)[c]
// Wave per node, 4 waves/block, no barriers.
// ---------------------------------------------------------------------------
__global__ __launch_bounds__(256) void gather_kernel(
    const float* __restrict__ h_src, const int* __restrict__ off,
    const int* __restrict__ srcg, const float* __restrict__ sh,
    const float* __restrict__ rbuf, const float* __restrict__ wtab,
    float* __restrict__ abuf, int n_out)
{
    int c = threadIdx.x & 63;
    int n = __builtin_amdgcn_readfirstlane(blockIdx.x * 4 + (threadIdx.x >> 6));
    if (n >= n_out) return;
    int e0 = off[n], e1 = off[n + 1];
    float acc[SH_DIM];
#pragma unroll
    for (int i = 0; i < SH_DIM; ++i) acc[i] = 0.0f;
    const float scale = (float)TBL / RMAXT;
    for (int p = e0; p < e1; ++p) {
        float rr = rbuf[p];                    // wave-uniform
        float x = rr * scale;
        int i0 = (int)x;
        float f = x - (float)i0;
        const float* tp = wtab + (size_t)i0 * MUL;
        float w0 = tp[c];
        float w1 = tp[MUL + c];
        float wv = fmaf(w1 - w0, f, w0);
        float s = h_src[(size_t)srcg[p] * FEAT + c];
        float sw = s * wv;
        const float* shp = sh + (size_t)p * SH_DIM;  // wave-uniform
#pragma unroll
        for (int i = 0; i < SH_DIM; ++i) acc[i] += shp[i] * sw;
    }
    const float isk = 0.22360679774997896f;  // 1/sqrt(20)
#pragma unroll
    for (int i = 0; i < SH_DIM; ++i)
        abuf[(size_t)n * FEAT + i * MUL + c] = acc[i] * isk;
}

// ---------------------------------------------------------------------------
// Per-l linear + gate + activation + residual. blockIdx.y: 0 -> l0+silu,
// 1 -> l1 (3 rows, gated), 2 -> l2 (5 rows, gated). Gate recomputed in y=1,2.
// ---------------------------------------------------------------------------
__global__ __launch_bounds__(256) void linear_kernel(
    const float* __restrict__ abuf, const float* __restrict__ base,
    float* __restrict__ outb,
    const float* __restrict__ Wl, const float* __restrict__ Wg, int n_out)
{
    int c = threadIdx.x & 63;
    int wid = __builtin_amdgcn_readfirstlane(blockIdx.x * 4 + (threadIdx.x >> 6));
    int nw = gridDim.x * 4;
    int y = blockIdx.y;

    if (y == 0) {
        float wl0[MUL];
#pragma unroll
        for (int k = 0; k < MUL; ++k) wl0[k] = Wl[k * MUL + c];
        for (int n = wid; n < n_out; n += nw) {
            const float* ar = abuf + (size_t)n * FEAT;  // row i=0, uniform
            float u = 0.0f;
#pragma unroll
            for (int k = 0; k < MUL; ++k) u += ar[k] * wl0[k];
            size_t idx = (size_t)n * FEAT + c;
            outb[idx] = base[idx] + silu_f(u);
        }
    } else {
        int ibase = (y == 1) ? 1 : 4;
        int ni = (y == 1) ? 3 : 5;
        const float* W = Wl + (size_t)y * MUL * MUL;
        float wcol[MUL], wg[MUL];
#pragma unroll
        for (int k = 0; k < MUL; ++k) { wcol[k] = W[k * MUL + c]; wg[k] = Wg[k * MUL + c]; }
        for (int n = wid; n < n_out; n += nw) {
            const float* a0 = abuf + (size_t)n * FEAT;  // row 0 for gate
            float g = 0.0f;
#pragma unroll
            for (int k = 0; k < MUL; ++k) g += a0[k] * wg[k];
            g = sigmoid_f(g);
            for (int ii = 0; ii < ni; ++ii) {
                const float* ar = a0 + (size_t)(ibase + ii) * MUL;
                float u = 0.0f;
#pragma unroll
                for (int k = 0; k < MUL; ++k) u += ar[k] * wcol[k];
                size_t idx = (size_t)n * FEAT + (size_t)(ibase + ii) * MUL + c;
                outb[idx] = base[idx] + u * g;
            }
        }
    }
}

// ---------------------------------------------------------------------------
// Readout: out[n] = dot(p[n,0,:], W_out[:,0])
// ---------------------------------------------------------------------------
__global__ __launch_bounds__(64) void out_kernel(const float* __restrict__ p,
                                                 const float* __restrict__ Wout,
                                                 float* __restrict__ out)
{
    int n = blockIdx.x;
    int c = threadIdx.x;
    float v = p[(size_t)n * FEAT + c] * Wout[c];
#pragma unroll
    for (int o = 32; o > 0; o >>= 1) v += __shfl_down(v, o, 64);
    if (c == 0) out[n] = v;
}

// ---------------------------------------------------------------------------
extern "C" void kernel_launch(void* const* d_in, const int* in_sizes, int n_in,
                              void* d_out, int out_size, void* d_ws, size_t ws_size,
                              hipStream_t stream)
{
    const float* atom_xyz  = (const float*)d_in[0];
    const float* a_disp    = (const float*)d_in[1];
    const float* cell      = (const float*)d_in[2];
    const float* probe_xyz = (const float*)d_in[3];
    const float* p_disp    = (const float*)d_in[4];
    const float* W_embed   = (const float*)d_in[5];
    const float* Wr1       = (const float*)d_in[6];
    const float* br1       = (const float*)d_in[7];
    const float* Wr2       = (const float*)d_in[8];
    const float* br2       = (const float*)d_in[9];
    const float* Wl        = (const float*)d_in[10];
    const float* Wg        = (const float*)d_in[11];
    const float* pWr1      = (const float*)d_in[12];
    const float* pbr1      = (const float*)d_in[13];
    const float* pWr2      = (const float*)d_in[14];
    const float* pbr2      = (const float*)d_in[15];
    const float* pWl       = (const float*)d_in[16];
    const float* pWg       = (const float*)d_in[17];
    const float* W_out     = (const float*)d_in[18];
    const int*   atom_edges  = (const int*)d_in[19];
    const int*   probe_edges = (const int*)d_in[20];
    const int*   nodes       = (const int*)d_in[21];
    float* out = (float*)d_out;

    char* w = (char*)d_ws;
    auto alloc = [&](size_t bytes) -> void* {
        void* r = (void*)w;
        w += (bytes + 255) & ~(size_t)255;
        return r;
    };
    float* sh_a   = (float*)alloc((size_t)ET * 9 * 4);
    float* rbuf_a = (float*)alloc((size_t)ET * 4);
    int*   src_a  = (int*)alloc((size_t)ET * 4);
    int*   cnt_a  = (int*)alloc((size_t)NA * 4);
    int*   off_a  = (int*)alloc((size_t)(NA + 1) * 4);
    int*   cur_a  = (int*)alloc((size_t)NA * 4);
    float* sh_p   = (float*)alloc((size_t)PET * 9 * 4);
    float* rbuf_p = (float*)alloc((size_t)PET * 4);
    int*   src_p  = (int*)alloc((size_t)PET * 4);
    int*   cnt_p  = (int*)alloc((size_t)NP * 4);
    int*   off_p  = (int*)alloc((size_t)(NP + 1) * 4);
    int*   cur_p  = (int*)alloc((size_t)NP * 4);
    float* h0     = (float*)alloc((size_t)NA * FEAT * 4);
    float* rep0   = (float*)alloc((size_t)NA * FEAT * 4);
    float* rep1   = (float*)alloc((size_t)NA * FEAT * 4);
    float* rep2   = (float*)alloc((size_t)NA * FEAT * 4);
    float* pbuf   = (float*)alloc((size_t)NP * FEAT * 4);
    float* abuf   = (float*)alloc((size_t)NP * FEAT * 4);
    float* w1t    = (float*)alloc((size_t)6 * HID * NBc * 4);
    float* wtab   = (float*)alloc((size_t)6 * TBL * MUL * 4);

    hipMemsetAsync(cnt_a, 0, (size_t)NA * 4, stream);
    hipMemsetAsync(cnt_p, 0, (size_t)NP * 4, stream);
    hipMemsetAsync(pbuf, 0, (size_t)NP * FEAT * 4, stream);

    // CSR build + geometry in CSR order
    count_kernel<<<(ET + 255) / 256, 256, 0, stream>>>(atom_edges, cnt_a, Ec, ET, Nc);
    count_kernel<<<(PET + 255) / 256, 256, 0, stream>>>(probe_edges, cnt_p, PEc, PET, Pc);
    scan_kernel<<<1, 256, 0, stream>>>(cnt_a, off_a, cur_a, NA);
    scan_kernel<<<1, 256, 0, stream>>>(cnt_p, off_p, cur_p, NP);
    geom_kernel<<<(ET + 255) / 256, 256, 0, stream>>>(
        atom_xyz, atom_xyz, atom_edges, a_disp, cell, cur_a,
        sh_a, rbuf_a, src_a, Ec, ET, Nc, Nc);
    geom_kernel<<<(PET + 255) / 256, 256, 0, stream>>>(
        atom_xyz, probe_xyz, probe_edges, p_disp, cell, cur_p,
        sh_p, rbuf_p, src_p, PEc, PET, Nc, Pc);

    // radial-MLP tables for all 6 layers (one launch)
    transpose_w1_kernel<<<(6 * HID * NBc + 255) / 256, 256, 0, stream>>>(Wr1, pWr1, w1t);
    table_kernel<<<6 * (TBL / 64), 256, 0, stream>>>(
        w1t, br1, pbr1, Wr2, pWr2, br2, pbr2, wtab);

    embed_kernel<<<(NA * FEAT + 255) / 256, 256, 0, stream>>>(nodes, W_embed, h0);

    const float* hprev = h0;
    float* reps[3] = {rep0, rep1, rep2};
    dim3 lingrid(256, 3);

    // atom layers
    for (int t = 0; t < Tc; ++t) {
        gather_kernel<<<NA / 4, 256, 0, stream>>>(
            hprev, off_a, src_a, sh_a, rbuf_a,
            wtab + (size_t)t * TBL * MUL, abuf, NA);
        linear_kernel<<<lingrid, 256, 0, stream>>>(
            abuf, hprev, reps[t],
            Wl + (size_t)t * 3 * MUL * MUL, Wg + (size_t)t * MUL * MUL, NA);
        hprev = reps[t];
    }

    // probe layers (accumulate into pbuf)
    for (int t = 0; t < Tc; ++t) {
        gather_kernel<<<NP / 4, 256, 0, stream>>>(
            reps[t], off_p, src_p, sh_p, rbuf_p,
            wtab + (size_t)(3 + t) * TBL * MUL, abuf, NP);
        linear_kernel<<<lingrid, 256, 0, stream>>>(
            abuf, pbuf, pbuf,
            pWl + (size_t)t * 3 * MUL * MUL, pWg + (size_t)t * MUL * MUL, NP);
    }

    out_kernel<<<NP, 64, 0, stream>>>(pbuf, W_out, out);
}

// Round 6
// 176.813 us; speedup vs baseline: 5.2992x; 1.5318x over previous
//
#include <hip/hip_runtime.h>
#include <math.h>

#define Bc 4
#define Nc 512
#define Pc 1024
#define Kc 20
#define MUL 64
#define NBc 20
#define HID 100
#define Tc 3
#define CUTc 4.0f
#define Ec (Nc * Kc)        /* 10240 */
#define PEc (Pc * Kc)       /* 20480 */
#define NA (Bc * Nc)        /* 2048 */
#define NP (Bc * Pc)        /* 4096 */
#define ET (Bc * Ec)        /* 40960 */
#define PET (Bc * PEc)      /* 81920 */
#define TBL 2048            /* w-table points over r in [0, RMAXT] */
#define RMAXT 6.5f          /* rbf(r) ~ 0 for r > 5 (centers end at 4, sigma 0.2) */

__device__ __forceinline__ float silu_f(float x) { return x / (1.0f + __expf(-x)); }

// ---------------------------------------------------------------------------
// Count edges per destination (atom + probe graphs in one launch)
// ---------------------------------------------------------------------------
__global__ void count_all_kernel(const int* __restrict__ a_edges,
                                 const int* __restrict__ p_edges,
                                 int* __restrict__ cnt_a, int* __restrict__ cnt_p)
{
    int e = blockIdx.x * 256 + threadIdx.x;
    if (e >= ET + PET) return;
    if (e < ET) {
        atomicAdd(&cnt_a[a_edges[e * 2 + 1] + (e / Ec) * Nc], 1);
    } else {
        int el = e - ET;
        atomicAdd(&cnt_p[p_edges[el * 2 + 1] + (el / PEc) * Pc], 1);
    }
}

// ---------------------------------------------------------------------------
// Exclusive scans: block 0 -> atom (NA), block 1 -> probe (NP)
// ---------------------------------------------------------------------------
__global__ void scan_all_kernel(const int* __restrict__ cnt_a, int* __restrict__ off_a,
                                int* __restrict__ cur_a,
                                const int* __restrict__ cnt_p, int* __restrict__ off_p,
                                int* __restrict__ cur_p)
{
    const int* cnt; int* off; int* cur; int n;
    if (blockIdx.x == 0) { cnt = cnt_a; off = off_a; cur = cur_a; n = NA; }
    else                 { cnt = cnt_p; off = off_p; cur = cur_p; n = NP; }
    __shared__ int part[256];
    int t = threadIdx.x;
    int per = (n + 255) / 256;
    int lo = t * per, hi = min(lo + per, n);
    int s = 0;
    for (int i = lo; i < hi; ++i) s += cnt[i];
    part[t] = s;
    __syncthreads();
    if (t == 0) {
        int run = 0;
        for (int i = 0; i < 256; ++i) { int v = part[i]; part[i] = run; run += v; }
        off[n] = run;
    }
    __syncthreads();
    int run = part[t];
    for (int i = lo; i < hi; ++i) { off[i] = run; cur[i] = run; run += cnt[i]; }
}

// ---------------------------------------------------------------------------
// Geometry (both graphs): edge length r + global src index, in CSR order.
// sh is dead code (only sh[0]=1 reaches the output), so it is not computed.
// ---------------------------------------------------------------------------
__global__ void geom_all_kernel(const float* __restrict__ apos,
                                const float* __restrict__ ppos,
                                const int* __restrict__ a_edges,
                                const int* __restrict__ p_edges,
                                const float* __restrict__ a_disp,
                                const float* __restrict__ p_disp,
                                const float* __restrict__ cell,
                                int* __restrict__ cur_a, int* __restrict__ cur_p,
                                float* __restrict__ r_a, float* __restrict__ r_p,
                                int* __restrict__ s_a, int* __restrict__ s_p)
{
    int e = blockIdx.x * 256 + threadIdx.x;
    if (e >= ET + PET) return;
    const int* edges; const float* displ; const float* pdst;
    int* cur; float* rout; int* sout;
    int el, Eper, dst_stride;
    if (e < ET) {
        el = e; edges = a_edges; displ = a_disp; pdst = apos;
        Eper = Ec; dst_stride = Nc; cur = cur_a; rout = r_a; sout = s_a;
    } else {
        el = e - ET; edges = p_edges; displ = p_disp; pdst = ppos;
        Eper = PEc; dst_stride = Pc; cur = cur_p; rout = r_p; sout = s_p;
    }
    int b = el / Eper;
    int sg = edges[el * 2 + 0] + b * Nc;
    int dg = edges[el * 2 + 1] + b * dst_stride;
    const float* C = cell + b * 9;
    float d0 = displ[el * 3 + 0], d1 = displ[el * 3 + 1], d2 = displ[el * 3 + 2];
    float dx = d0 * C[0] + d1 * C[3] + d2 * C[6];
    float dy = d0 * C[1] + d1 * C[4] + d2 * C[7];
    float dz = d0 * C[2] + d1 * C[5] + d2 * C[8];
    float vx = pdst[dg * 3 + 0] - (apos[sg * 3 + 0] + dx);
    float vy = pdst[dg * 3 + 1] - (apos[sg * 3 + 1] + dy);
    float vz = pdst[dg * 3 + 2] - (apos[sg * 3 + 2] + dz);
    float r = sqrtf(vx * vx + vy * vy + vz * vz);
    int pos = atomicAdd(&cur[dg], 1);
    rout[pos] = r;
    sout[pos] = sg;
}

// ---------------------------------------------------------------------------
// W1 transpose: w1t_all[t6][j][k] = W1[t6][k][j]  (t6: 0-2 atom, 3-5 probe)
// ---------------------------------------------------------------------------
__global__ void transpose_w1_kernel(const float* __restrict__ Wr1,
                                    const float* __restrict__ pWr1,
                                    float* __restrict__ w1t_all)
{
    int idx = blockIdx.x * 256 + threadIdx.x;
    if (idx >= 6 * HID * NBc) return;
    int t6 = idx / (HID * NBc);
    int rem = idx % (HID * NBc);
    int j = rem / NBc;
    int k = rem % NBc;
    const float* src = (t6 < 3) ? (Wr1 + (size_t)t6 * NBc * HID)
                                : (pWr1 + (size_t)(t6 - 3) * NBc * HID);
    w1t_all[idx] = src[k * HID + j];
}

// ---------------------------------------------------------------------------
// Embedding, row 0 only: h0row[a][c] = W_embed[nodes[a]][c]
// ---------------------------------------------------------------------------
__global__ void embed_kernel(const int* __restrict__ nodes, const float* __restrict__ Wemb,
                             float* __restrict__ h0row)
{
    int idx = blockIdx.x * 256 + threadIdx.x;
    if (idx >= NA * MUL) return;
    int a = idx >> 6;
    int c = idx & 63;
    h0row[idx] = Wemb[nodes[a] * MUL + c];
}

// ---------------------------------------------------------------------------
// Radial-MLP table: wtab[ly][i][c] = MLP_ly(rbf(r_i)), r_i = i*RMAXT/TBL,
// all 6 layer-weight-sets in one launch. Block = 4 waves on same 64 points;
// wave q -> channels [16q,16q+16). Weights via wave-uniform scalar operands.
// ---------------------------------------------------------------------------
__global__ __launch_bounds__(256) void table_kernel(
    const float* __restrict__ w1t,   // (6,100,20) transposed
    const float* __restrict__ br1,  const float* __restrict__ pbr1,
    const float* __restrict__ Wr2,  const float* __restrict__ pWr2,
    const float* __restrict__ br2,  const float* __restrict__ pbr2,
    float* __restrict__ wtab)        // (6, TBL, 64)
{
    int lane = threadIdx.x & 63;
    int q = __builtin_amdgcn_readfirstlane(threadIdx.x >> 6);
    int g = blockIdx.x;
    int ly = g / (TBL / 64);
    int grp = g % (TBL / 64);
    int t3 = (ly < 3) ? ly : ly - 3;
    const float* w1 = w1t + (size_t)ly * HID * NBc;
    const float* b1 = ((ly < 3) ? br1 : pbr1) + (size_t)t3 * HID;
    const float* w2 = ((ly < 3) ? Wr2 : pWr2) + (size_t)t3 * HID * MUL;
    const float* b2 = ((ly < 3) ? br2 : pbr2) + (size_t)t3 * MUL;

    int i = grp * 64 + lane;
    float r = (float)i * (RMAXT / (float)TBL);
    float rb[NBc];
    const float step = CUTc / (NBc - 1);
    const float inv_sigma = (float)NBc / CUTc;
#pragma unroll
    for (int k = 0; k < NBc; ++k) {
        float t = (r - k * step) * inv_sigma;
        rb[k] = __expf(-t * t);
    }

    const float* w2q = w2 + q * 16;
    float acc[16];
#pragma unroll
    for (int cc = 0; cc < 16; ++cc) acc[cc] = b2[q * 16 + cc];

    for (int ch = 0; ch < 10; ++ch) {
        float h[10];
#pragma unroll
        for (int jj = 0; jj < 10; ++jj) {
            int j = ch * 10 + jj;
            const float* wr = w1 + (size_t)j * NBc;  // uniform row
            float s = b1[j];
#pragma unroll
            for (int k = 0; k < NBc; ++k) s += rb[k] * wr[k];
            h[jj] = silu_f(s);
        }
#pragma unroll
        for (int jj = 0; jj < 10; ++jj) {
            int j = ch * 10 + jj;
            const float* w2r = w2q + (size_t)j * MUL;  // uniform row slice
            float hv = h[jj];
#pragma unroll
            for (int cc = 0; cc < 16; ++cc) acc[cc] += hv * w2r[cc];
        }
    }

    float4* op = (float4*)(wtab + ((size_t)ly * TBL + i) * MUL + q * 16);
#pragma unroll
    for (int v = 0; v < 4; ++v)
        op[v] = make_float4(acc[v * 4], acc[v * 4 + 1], acc[v * 4 + 2], acc[v * 4 + 3]);
}

// ---------------------------------------------------------------------------
// Fused conv layer (row-0 only): per dst node n:
//   a[c]   = (1/sqrt(K)) * sum_e hsrc[src_e][c] * lerp(wtab, r_e)[c]
//   u[c]   = sum_cp a[cp] * Wl0[cp][c]      (via per-wave LDS tile, no barrier)
//   res[c] = (base ? base[n][c] : 0) + silu(u[c])
//   Wout ? out[n] = dot(res, Wout) : outb[n][c] = res[c]
// Wave per node, 4 waves/block.
// ---------------------------------------------------------------------------
__global__ __launch_bounds__(256) void layer_kernel(
    const float* __restrict__ hsrc,   // (n_src,64) row-0 feats
    const float* __restrict__ base,   // (n_out,64) or nullptr (treated as 0)
    float* __restrict__ outb,         // (n_out,64)
    const int* __restrict__ off, const int* __restrict__ srcg,
    const float* __restrict__ rbuf, const float* __restrict__ wtab,
    const float* __restrict__ Wl0,    // (64,64)
    const float* __restrict__ Wout,   // nullptr unless final layer
    float* __restrict__ fout,         // final output (n_out)
    int n_out)
{
    __shared__ float tile[4][64];
    int c = threadIdx.x & 63;
    int w = threadIdx.x >> 6;
    int n = blockIdx.x * 4 + w;
    if (n >= n_out) return;

    float wcol[64];
#pragma unroll
    for (int k = 0; k < 64; ++k) wcol[k] = Wl0[k * 64 + c];

    int e0 = off[n], e1 = off[n + 1];
    float acc = 0.0f;
    const float scale = (float)TBL / RMAXT;
    for (int p = e0; p < e1; ++p) {
        float rr = rbuf[p];                              // wave-uniform
        float x = fminf(rr * scale, (float)TBL - 1.001f); // clamp: w const beyond table
        int i0 = (int)x;
        float f = x - (float)i0;
        const float* tp = wtab + (size_t)i0 * MUL;
        float w0 = tp[c];
        float w1 = tp[MUL + c];
        float wv = fmaf(w1 - w0, f, w0);
        float s = hsrc[(size_t)srcg[p] * MUL + c];
        acc = fmaf(s, wv, acc);
    }
    acc *= 0.22360679774997896f;  // 1/sqrt(20)

    tile[w][c] = acc;             // same-wave LDS RAW; no barrier needed
    float u = 0.0f;
#pragma unroll
    for (int k4 = 0; k4 < 16; ++k4) {
        float4 av = *(const float4*)&tile[w][k4 * 4];   // broadcast reads
        u = fmaf(av.x, wcol[k4 * 4 + 0], u);
        u = fmaf(av.y, wcol[k4 * 4 + 1], u);
        u = fmaf(av.z, wcol[k4 * 4 + 2], u);
        u = fmaf(av.w, wcol[k4 * 4 + 3], u);
    }
    float val = silu_f(u);
    float bv = base ? base[(size_t)n * MUL + c] : 0.0f;
    float res = bv + val;

    if (Wout) {
        float v = res * Wout[c];
#pragma unroll
        for (int o = 32; o > 0; o >>= 1) v += __shfl_down(v, o, 64);
        if (c == 0) fout[n] = v;
    } else {
        outb[(size_t)n * MUL + c] = res;
    }
}

// ---------------------------------------------------------------------------
extern "C" void kernel_launch(void* const* d_in, const int* in_sizes, int n_in,
                              void* d_out, int out_size, void* d_ws, size_t ws_size,
                              hipStream_t stream)
{
    const float* atom_xyz  = (const float*)d_in[0];
    const float* a_disp    = (const float*)d_in[1];
    const float* cell      = (const float*)d_in[2];
    const float* probe_xyz = (const float*)d_in[3];
    const float* p_disp    = (const float*)d_in[4];
    const float* W_embed   = (const float*)d_in[5];
    const float* Wr1       = (const float*)d_in[6];
    const float* br1       = (const float*)d_in[7];
    const float* Wr2       = (const float*)d_in[8];
    const float* br2       = (const float*)d_in[9];
    const float* Wl        = (const float*)d_in[10];
    const float* pWr1      = (const float*)d_in[12];
    const float* pbr1      = (const float*)d_in[13];
    const float* pWr2      = (const float*)d_in[14];
    const float* pbr2      = (const float*)d_in[15];
    const float* pWl       = (const float*)d_in[16];
    const float* W_out     = (const float*)d_in[18];
    const int*   atom_edges  = (const int*)d_in[19];
    const int*   probe_edges = (const int*)d_in[20];
    const int*   nodes       = (const int*)d_in[21];
    float* out = (float*)d_out;

    char* w = (char*)d_ws;
    auto alloc = [&](size_t bytes) -> void* {
        void* r = (void*)w;
        w += (bytes + 255) & ~(size_t)255;
        return r;
    };
    int*   cnt_both = (int*)alloc((size_t)(NA + NP) * 4);  // cnt_a | cnt_p contiguous
    int*   cnt_a  = cnt_both;
    int*   cnt_p  = cnt_both + NA;
    int*   off_a  = (int*)alloc((size_t)(NA + 1) * 4);
    int*   cur_a  = (int*)alloc((size_t)NA * 4);
    int*   off_p  = (int*)alloc((size_t)(NP + 1) * 4);
    int*   cur_p  = (int*)alloc((size_t)NP * 4);
    float* rbuf_a = (float*)alloc((size_t)ET * 4);
    int*   src_a  = (int*)alloc((size_t)ET * 4);
    float* rbuf_p = (float*)alloc((size_t)PET * 4);
    int*   src_p  = (int*)alloc((size_t)PET * 4);
    float* h0row  = (float*)alloc((size_t)NA * MUL * 4);
    float* rep0   = (float*)alloc((size_t)NA * MUL * 4);
    float* rep1   = (float*)alloc((size_t)NA * MUL * 4);
    float* rep2   = (float*)alloc((size_t)NA * MUL * 4);
    float* p0     = (float*)alloc((size_t)NP * MUL * 4);
    float* w1t    = (float*)alloc((size_t)6 * HID * NBc * 4);
    float* wtab   = (float*)alloc((size_t)6 * TBL * MUL * 4);

    hipMemsetAsync(cnt_both, 0, (size_t)(NA + NP) * 4, stream);

    // CSR build + geometry (r only) in CSR order
    count_all_kernel<<<(ET + PET + 255) / 256, 256, 0, stream>>>(
        atom_edges, probe_edges, cnt_a, cnt_p);
    scan_all_kernel<<<2, 256, 0, stream>>>(cnt_a, off_a, cur_a, cnt_p, off_p, cur_p);
    geom_all_kernel<<<(ET + PET + 255) / 256, 256, 0, stream>>>(
        atom_xyz, probe_xyz, atom_edges, probe_edges, a_disp, p_disp, cell,
        cur_a, cur_p, rbuf_a, rbuf_p, src_a, src_p);

    // radial-MLP tables for all 6 layers
    transpose_w1_kernel<<<(6 * HID * NBc + 255) / 256, 256, 0, stream>>>(Wr1, pWr1, w1t);
    table_kernel<<<6 * (TBL / 64), 256, 0, stream>>>(
        w1t, br1, pbr1, Wr2, pWr2, br2, pbr2, wtab);

    embed_kernel<<<(NA * MUL + 255) / 256, 256, 0, stream>>>(nodes, W_embed, h0row);

    const float* hprev = h0row;
    float* reps[3] = {rep0, rep1, rep2};

    for (int t = 0; t < Tc; ++t) {
        // atom layer t: reps[t] = hprev + silu(gather(hprev) @ Wl0)
        layer_kernel<<<NA / 4, 256, 0, stream>>>(
            hprev, hprev, reps[t], off_a, src_a, rbuf_a,
            wtab + (size_t)t * TBL * MUL,
            Wl + (size_t)t * 3 * MUL * MUL,
            nullptr, nullptr, NA);
        hprev = reps[t];
        // probe layer t: p0 (+)= silu(gather(reps[t]) @ pWl0); final fuses W_out dot
        layer_kernel<<<NP / 4, 256, 0, stream>>>(
            reps[t], (t == 0) ? nullptr : p0, p0, off_p, src_p, rbuf_p,
            wtab + (size_t)(3 + t) * TBL * MUL,
            pWl + (size_t)t * 3 * MUL * MUL,
            (t == Tc - 1) ? W_out : nullptr, out, NP);
    }
}

// Round 7
// 113.920 us; speedup vs baseline: 8.2248x; 1.5521x over previous
//
#include <hip/hip_runtime.h>
#include <math.h>

#define Bc 4
#define Nc 512
#define Pc 1024
#define Kc 20
#define MUL 64
#define NBc 20
#define HID 100
#define Tc 3
#define CUTc 4.0f
#define Ec (Nc * Kc)        /* 10240 */
#define PEc (Pc * Kc)       /* 20480 */
#define NA (Bc * Nc)        /* 2048 */
#define NP (Bc * Pc)        /* 4096 */
#define ET (Bc * Ec)        /* 40960 */
#define PET (Bc * PEc)      /* 81920 */
#define TBL 2048            /* w-table points over r in [0, RMAXT] */
#define RMAXT 6.5f          /* rbf(r) ~ 0 for r > 5 (centers end at 4, sigma 0.2) */

__device__ __forceinline__ float silu_f(float x) { return x / (1.0f + __expf(-x)); }
__device__ __forceinline__ float lane_bcast_f(float v, int l) {
    return __int_as_float(__builtin_amdgcn_readlane(__float_as_int(v), l));
}

// ---------------------------------------------------------------------------
// Count edges per destination (atom + probe graphs in one launch)
// ---------------------------------------------------------------------------
__global__ void count_all_kernel(const int* __restrict__ a_edges,
                                 const int* __restrict__ p_edges,
                                 int* __restrict__ cnt_a, int* __restrict__ cnt_p)
{
    int e = blockIdx.x * 256 + threadIdx.x;
    if (e >= ET + PET) return;
    if (e < ET) {
        atomicAdd(&cnt_a[a_edges[e * 2 + 1] + (e / Ec) * Nc], 1);
    } else {
        int el = e - ET;
        atomicAdd(&cnt_p[p_edges[el * 2 + 1] + (el / PEc) * Pc], 1);
    }
}

// ---------------------------------------------------------------------------
// Exclusive scans: block 0 -> atom (NA), block 1 -> probe (NP)
// ---------------------------------------------------------------------------
__global__ void scan_all_kernel(const int* __restrict__ cnt_a, int* __restrict__ off_a,
                                int* __restrict__ cur_a,
                                const int* __restrict__ cnt_p, int* __restrict__ off_p,
                                int* __restrict__ cur_p)
{
    const int* cnt; int* off; int* cur; int n;
    if (blockIdx.x == 0) { cnt = cnt_a; off = off_a; cur = cur_a; n = NA; }
    else                 { cnt = cnt_p; off = off_p; cur = cur_p; n = NP; }
    __shared__ int part[256];
    int t = threadIdx.x;
    int per = (n + 255) / 256;
    int lo = t * per, hi = min(lo + per, n);
    int s = 0;
    for (int i = lo; i < hi; ++i) s += cnt[i];
    part[t] = s;
    __syncthreads();
    if (t == 0) {
        int run = 0;
        for (int i = 0; i < 256; ++i) { int v = part[i]; part[i] = run; run += v; }
        off[n] = run;
    }
    __syncthreads();
    int run = part[t];
    for (int i = lo; i < hi; ++i) { off[i] = run; cur[i] = run; run += cnt[i]; }
}

// ---------------------------------------------------------------------------
// Geometry (both graphs): edge length r + global src index, in CSR order.
// (sh rows 1..8, gate and l=1/2 paths are dead code w.r.t. the output.)
// ---------------------------------------------------------------------------
__global__ void geom_all_kernel(const float* __restrict__ apos,
                                const float* __restrict__ ppos,
                                const int* __restrict__ a_edges,
                                const int* __restrict__ p_edges,
                                const float* __restrict__ a_disp,
                                const float* __restrict__ p_disp,
                                const float* __restrict__ cell,
                                int* __restrict__ cur_a, int* __restrict__ cur_p,
                                float* __restrict__ r_a, float* __restrict__ r_p,
                                int* __restrict__ s_a, int* __restrict__ s_p)
{
    int e = blockIdx.x * 256 + threadIdx.x;
    if (e >= ET + PET) return;
    const int* edges; const float* displ; const float* pdst;
    int* cur; float* rout; int* sout;
    int el, Eper, dst_stride;
    if (e < ET) {
        el = e; edges = a_edges; displ = a_disp; pdst = apos;
        Eper = Ec; dst_stride = Nc; cur = cur_a; rout = r_a; sout = s_a;
    } else {
        el = e - ET; edges = p_edges; displ = p_disp; pdst = ppos;
        Eper = PEc; dst_stride = Pc; cur = cur_p; rout = r_p; sout = s_p;
    }
    int b = el / Eper;
    int sg = edges[el * 2 + 0] + b * Nc;
    int dg = edges[el * 2 + 1] + b * dst_stride;
    const float* C = cell + b * 9;
    float d0 = displ[el * 3 + 0], d1 = displ[el * 3 + 1], d2 = displ[el * 3 + 2];
    float dx = d0 * C[0] + d1 * C[3] + d2 * C[6];
    float dy = d0 * C[1] + d1 * C[4] + d2 * C[7];
    float dz = d0 * C[2] + d1 * C[5] + d2 * C[8];
    float vx = pdst[dg * 3 + 0] - (apos[sg * 3 + 0] + dx);
    float vy = pdst[dg * 3 + 1] - (apos[sg * 3 + 1] + dy);
    float vz = pdst[dg * 3 + 2] - (apos[sg * 3 + 2] + dz);
    float r = sqrtf(vx * vx + vy * vy + vz * vz);
    int pos = atomicAdd(&cur[dg], 1);
    rout[pos] = r;
    sout[pos] = sg;
}

// ---------------------------------------------------------------------------
// Embedding, row 0 only: h0row[a][c] = W_embed[nodes[a]][c]
// ---------------------------------------------------------------------------
__global__ void embed_kernel(const int* __restrict__ nodes, const float* __restrict__ Wemb,
                             float* __restrict__ h0row)
{
    int idx = blockIdx.x * 256 + threadIdx.x;
    if (idx >= NA * MUL) return;
    int a = idx >> 6;
    int c = idx & 63;
    h0row[idx] = Wemb[nodes[a] * MUL + c];
}

// ---------------------------------------------------------------------------
// Table phase A: H[ly][i][j] = silu(b1[j] + sum_k rbf_k(r_i) * W1[ly][k][j])
// Thread per (ly, i, j) -> 1.23M threads, fully latency-tolerant.
// W1 in ORIGINAL layout: consecutive j => consecutive addresses (coalesced).
// ---------------------------------------------------------------------------
__global__ __launch_bounds__(256) void hidden_kernel(
    const float* __restrict__ Wr1, const float* __restrict__ pWr1,
    const float* __restrict__ br1, const float* __restrict__ pbr1,
    float* __restrict__ H)           // (6*TBL, 100)
{
    int id = blockIdx.x * 256 + threadIdx.x;
    if (id >= 6 * TBL * HID) return;
    int j = id % HID;
    int rest = id / HID;
    int i = rest % TBL;
    int ly = rest / TBL;
    int t3 = (ly < 3) ? ly : ly - 3;
    const float* w1 = ((ly < 3) ? Wr1 : pWr1) + (size_t)t3 * NBc * HID;
    const float* b1 = ((ly < 3) ? br1 : pbr1) + (size_t)t3 * HID;

    float r = (float)i * (RMAXT / (float)TBL);
    const float step = CUTc / (NBc - 1);
    const float inv_sigma = (float)NBc / CUTc;
    float s = b1[j];
#pragma unroll
    for (int k = 0; k < NBc; ++k) {
        float t = (r - k * step) * inv_sigma;
        s = fmaf(__expf(-t * t), w1[k * HID + j], s);
    }
    H[id] = silu_f(s);
}

// ---------------------------------------------------------------------------
// Table phase B: wtab[ly][i][c] = b2[c] + sum_j H[ly][i][j] * W2[ly][j][c]
// Wave per (ly,i); lane = c. H row wave-uniform (s_load stream), W2 rows
// coalesced + L1-resident. 12288 waves -> 12/SIMD.
// ---------------------------------------------------------------------------
__global__ __launch_bounds__(256) void w2_kernel(
    const float* __restrict__ H,
    const float* __restrict__ Wr2, const float* __restrict__ pWr2,
    const float* __restrict__ br2, const float* __restrict__ pbr2,
    float* __restrict__ wtab)        // (6*TBL, 64)
{
    int c = threadIdx.x & 63;
    int wid = __builtin_amdgcn_readfirstlane(blockIdx.x * 4 + (threadIdx.x >> 6));
    int ly = wid / TBL;
    int t3 = (ly < 3) ? ly : ly - 3;
    const float* w2 = ((ly < 3) ? Wr2 : pWr2) + (size_t)t3 * HID * MUL;
    const float* b2 = ((ly < 3) ? br2 : pbr2) + (size_t)t3 * MUL;
    const float* h = H + (size_t)wid * HID;   // wave-uniform row
    float acc = b2[c];
#pragma unroll 4
    for (int j = 0; j < HID; ++j)
        acc = fmaf(h[j], w2[(size_t)j * MUL + c], acc);
    wtab[(size_t)wid * MUL + c] = acc;
}

// ---------------------------------------------------------------------------
// Atom conv layer (row-0 only), wave per node, 4 waves/block.
// Edge r/src prefetched per 64-edge chunk via one lane-load + readlane
// broadcasts -> all wtab/hsrc addresses available early (deep load ILP).
// ---------------------------------------------------------------------------
__global__ __launch_bounds__(256) void layer_kernel(
    const float* __restrict__ hsrc,   // (n_src,64)
    const float* __restrict__ base,   // (n_out,64)
    float* __restrict__ outb,         // (n_out,64)
    const int* __restrict__ off, const int* __restrict__ srcg,
    const float* __restrict__ rbuf, const float* __restrict__ wtab,
    const float* __restrict__ Wl0,    // (64,64)
    int n_out)
{
    __shared__ float tile[4][64];
    int c = threadIdx.x & 63;
    int w = threadIdx.x >> 6;
    int n = blockIdx.x * 4 + w;
    if (n >= n_out) return;

    int e0 = off[n], e1 = off[n + 1];
    float acc = 0.0f;
    const float scale = (float)TBL / RMAXT;
    for (int bse = e0; bse < e1; bse += 64) {
        int mm = min(e1 - bse, 64);
        float rvec = 0.0f; int svec = 0;
        if (c < mm) { rvec = rbuf[bse + c]; svec = srcg[bse + c]; }
#pragma unroll 4
        for (int p = 0; p < mm; ++p) {
            float rr = lane_bcast_f(rvec, p);
            int sg = __builtin_amdgcn_readlane(svec, p);
            float x = fminf(rr * scale, (float)TBL - 1.001f);
            int i0 = (int)x;
            float f = x - (float)i0;
            const float* tp = wtab + (size_t)i0 * MUL;
            float w0 = tp[c];
            float w1 = tp[MUL + c];
            float wv = fmaf(w1 - w0, f, w0);
            acc = fmaf(hsrc[(size_t)sg * MUL + c], wv, acc);
        }
    }
    acc *= 0.22360679774997896f;  // 1/sqrt(20)

    tile[w][c] = acc;             // same-wave LDS RAW; no barrier needed
    float u = 0.0f;
#pragma unroll
    for (int k4 = 0; k4 < 16; ++k4) {
        float4 av = *(const float4*)&tile[w][k4 * 4];
        u = fmaf(av.x, Wl0[(k4 * 4 + 0) * 64 + c], u);
        u = fmaf(av.y, Wl0[(k4 * 4 + 1) * 64 + c], u);
        u = fmaf(av.z, Wl0[(k4 * 4 + 2) * 64 + c], u);
        u = fmaf(av.w, Wl0[(k4 * 4 + 3) * 64 + c], u);
    }
    outb[(size_t)n * MUL + c] = base[(size_t)n * MUL + c] + silu_f(u);
}

// ---------------------------------------------------------------------------
// Fused probe pipeline: all 3 probe conv layers + readout in one kernel.
// The 3 layers are independent (only summed), so per edge we share the
// r/src loads and accumulate 3 channels-vectors; epilogue does 3 GEMVs,
// sums silu's, and dots with W_out.
// ---------------------------------------------------------------------------
__global__ __launch_bounds__(256) void probe3_kernel(
    const float* __restrict__ rep0, const float* __restrict__ rep1,
    const float* __restrict__ rep2,
    const int* __restrict__ off, const int* __restrict__ srcg,
    const float* __restrict__ rbuf, const float* __restrict__ wtab, // + 3*TBL*64 = probe tables
    const float* __restrict__ pWl,   // (3,3,64,64); l0 slice per t
    const float* __restrict__ Wout,  // (64)
    float* __restrict__ out)         // (NP)
{
    __shared__ float tile[4][64];
    int c = threadIdx.x & 63;
    int w = threadIdx.x >> 6;
    int n = blockIdx.x * 4 + w;

    int e0 = off[n], e1 = off[n + 1];
    float acc0 = 0.0f, acc1 = 0.0f, acc2 = 0.0f;
    const float scale = (float)TBL / RMAXT;
    const float* wt0 = wtab;
    const float* wt1 = wtab + (size_t)TBL * MUL;
    const float* wt2 = wtab + (size_t)2 * TBL * MUL;
    for (int bse = e0; bse < e1; bse += 64) {
        int mm = min(e1 - bse, 64);
        float rvec = 0.0f; int svec = 0;
        if (c < mm) { rvec = rbuf[bse + c]; svec = srcg[bse + c]; }
#pragma unroll 2
        for (int p = 0; p < mm; ++p) {
            float rr = lane_bcast_f(rvec, p);
            int sg = __builtin_amdgcn_readlane(svec, p);
            float x = fminf(rr * scale, (float)TBL - 1.001f);
            int i0 = (int)x;
            float f = x - (float)i0;
            size_t rowo = (size_t)i0 * MUL + c;
            float wv0 = fmaf(wt0[rowo + MUL] - wt0[rowo], f, wt0[rowo]);
            float wv1 = fmaf(wt1[rowo + MUL] - wt1[rowo], f, wt1[rowo]);
            float wv2 = fmaf(wt2[rowo + MUL] - wt2[rowo], f, wt2[rowo]);
            size_t so = (size_t)sg * MUL + c;
            acc0 = fmaf(rep0[so], wv0, acc0);
            acc1 = fmaf(rep1[so], wv1, acc1);
            acc2 = fmaf(rep2[so], wv2, acc2);
        }
    }
    const float isk = 0.22360679774997896f;  // 1/sqrt(20)
    float res = 0.0f;
    float accs[3] = {acc0, acc1, acc2};
#pragma unroll
    for (int t = 0; t < 3; ++t) {
        tile[w][c] = accs[t] * isk;          // same-wave LDS RAW
        const float* W = pWl + (size_t)t * 3 * MUL * MUL;  // l0 slice
        float u = 0.0f;
#pragma unroll
        for (int k4 = 0; k4 < 16; ++k4) {
            float4 av = *(const float4*)&tile[w][k4 * 4];
            u = fmaf(av.x, W[(k4 * 4 + 0) * 64 + c], u);
            u = fmaf(av.y, W[(k4 * 4 + 1) * 64 + c], u);
            u = fmaf(av.z, W[(k4 * 4 + 2) * 64 + c], u);
            u = fmaf(av.w, W[(k4 * 4 + 3) * 64 + c], u);
        }
        res += silu_f(u);
    }

    float v = res * Wout[c];
#pragma unroll
    for (int o = 32; o > 0; o >>= 1) v += __shfl_down(v, o, 64);
    if (c == 0) out[n] = v;
}

// ---------------------------------------------------------------------------
extern "C" void kernel_launch(void* const* d_in, const int* in_sizes, int n_in,
                              void* d_out, int out_size, void* d_ws, size_t ws_size,
                              hipStream_t stream)
{
    const float* atom_xyz  = (const float*)d_in[0];
    const float* a_disp    = (const float*)d_in[1];
    const float* cell      = (const float*)d_in[2];
    const float* probe_xyz = (const float*)d_in[3];
    const float* p_disp    = (const float*)d_in[4];
    const float* W_embed   = (const float*)d_in[5];
    const float* Wr1       = (const float*)d_in[6];
    const float* br1       = (const float*)d_in[7];
    const float* Wr2       = (const float*)d_in[8];
    const float* br2       = (const float*)d_in[9];
    const float* Wl        = (const float*)d_in[10];
    const float* pWr1      = (const float*)d_in[12];
    const float* pbr1      = (const float*)d_in[13];
    const float* pWr2      = (const float*)d_in[14];
    const float* pbr2      = (const float*)d_in[15];
    const float* pWl       = (const float*)d_in[16];
    const float* W_out     = (const float*)d_in[18];
    const int*   atom_edges  = (const int*)d_in[19];
    const int*   probe_edges = (const int*)d_in[20];
    const int*   nodes       = (const int*)d_in[21];
    float* out = (float*)d_out;

    char* w = (char*)d_ws;
    auto alloc = [&](size_t bytes) -> void* {
        void* r = (void*)w;
        w += (bytes + 255) & ~(size_t)255;
        return r;
    };
    int*   cnt_both = (int*)alloc((size_t)(NA + NP) * 4);
    int*   cnt_a  = cnt_both;
    int*   cnt_p  = cnt_both + NA;
    int*   off_a  = (int*)alloc((size_t)(NA + 1) * 4);
    int*   cur_a  = (int*)alloc((size_t)NA * 4);
    int*   off_p  = (int*)alloc((size_t)(NP + 1) * 4);
    int*   cur_p  = (int*)alloc((size_t)NP * 4);
    float* rbuf_a = (float*)alloc((size_t)ET * 4);
    int*   src_a  = (int*)alloc((size_t)ET * 4);
    float* rbuf_p = (float*)alloc((size_t)PET * 4);
    int*   src_p  = (int*)alloc((size_t)PET * 4);
    float* h0row  = (float*)alloc((size_t)NA * MUL * 4);
    float* rep0   = (float*)alloc((size_t)NA * MUL * 4);
    float* rep1   = (float*)alloc((size_t)NA * MUL * 4);
    float* rep2   = (float*)alloc((size_t)NA * MUL * 4);
    float* Hbuf   = (float*)alloc((size_t)6 * TBL * HID * 4);
    float* wtab   = (float*)alloc((size_t)6 * TBL * MUL * 4);

    hipMemsetAsync(cnt_both, 0, (size_t)(NA + NP) * 4, stream);

    // CSR build + geometry (r only) in CSR order
    count_all_kernel<<<(ET + PET + 255) / 256, 256, 0, stream>>>(
        atom_edges, probe_edges, cnt_a, cnt_p);
    scan_all_kernel<<<2, 256, 0, stream>>>(cnt_a, off_a, cur_a, cnt_p, off_p, cur_p);
    geom_all_kernel<<<(ET + PET + 255) / 256, 256, 0, stream>>>(
        atom_xyz, probe_xyz, atom_edges, probe_edges, a_disp, p_disp, cell,
        cur_a, cur_p, rbuf_a, rbuf_p, src_a, src_p);

    // radial-MLP tables, two massively-parallel phases
    hidden_kernel<<<(6 * TBL * HID + 255) / 256, 256, 0, stream>>>(
        Wr1, pWr1, br1, pbr1, Hbuf);
    w2_kernel<<<6 * TBL / 4, 256, 0, stream>>>(
        Hbuf, Wr2, pWr2, br2, pbr2, wtab);

    embed_kernel<<<(NA * MUL + 255) / 256, 256, 0, stream>>>(nodes, W_embed, h0row);

    // atom layers (sequential residual chain)
    const float* hprev = h0row;
    float* reps[3] = {rep0, rep1, rep2};
    for (int t = 0; t < Tc; ++t) {
        layer_kernel<<<NA / 4, 256, 0, stream>>>(
            hprev, hprev, reps[t], off_a, src_a, rbuf_a,
            wtab + (size_t)t * TBL * MUL,
            Wl + (size_t)t * 3 * MUL * MUL, NA);
        hprev = reps[t];
    }

    // fused probe layers + readout
    probe3_kernel<<<NP / 4, 256, 0, stream>>>(
        rep0, rep1, rep2, off_p, src_p, rbuf_p,
        wtab + (size_t)3 * TBL * MUL, pWl, W_out, out);
}